// Round 11
// baseline (182.941 us; speedup 1.0000x reference)
//
#include <hip/hip_runtime.h>

#define EPS 1e-5f

namespace {
constexpr int HYPER = 14016;
constexpr int HID   = 192;
constexpr int A1    = 324;   // 18*18
constexpr int A2    = 256;   // 16*16
constexpr int P_TOT = 512;
constexpr int W1SZ  = 6144;  // 32*192
constexpr int WT2SZ = 7872;  // w2 (1728) + w3 (6144)
constexpr int R3OFF = 1728;  // w3 offset inside wt2

// workspace byte offsets
constexpr size_t WB1_B = 0;                       // bf16 w1 A-frag order [p][6144], 6,291,456 B
constexpr size_t WT2_B = 6291456;                 // fp32 w2+w3 [p][7872], 16,121,856 B
constexpr size_t X2_B  = WT2_B + 16121856;        // bf16 x2 [p][12][256][16], 50,331,648 B
constexpr size_t X3_B  = X2_B + 50331648;         // bf16 x3 [p][32][256], 8,388,608 B
constexpr size_t SUM_B = X3_B + 8388608;          // fp32 16 replicas x 832 floats
// per replica: [0:192) s1 [192:384) q1 [384:576) s2 [576:768) q2 [768:800) s3 [800:832) q3
constexpr int REP  = 832;                         // floats per replica
constexpr int NREP = 16;
}

typedef __attribute__((ext_vector_type(8))) short bf16x8;
typedef __attribute__((ext_vector_type(8))) unsigned short u16x8;
typedef __attribute__((ext_vector_type(4))) float f32x4;
typedef __attribute__((ext_vector_type(4))) unsigned int u32x4;

__device__ __forceinline__ float relu6f(float v) { return fminf(fmaxf(v, 0.f), 6.f); }

__device__ __forceinline__ float bf2f(unsigned int h) {
  return __uint_as_float(h << 16);
}
__device__ __forceinline__ unsigned short f2bf(float f) {
  unsigned int u = __float_as_uint(f);
  return (unsigned short)((u + 0x7FFFu + ((u >> 16) & 1u)) >> 16);
}

// sum the NREP replicas of a stats slot
__device__ __forceinline__ float rsum16(const float* __restrict__ base, int idx) {
  float s = 0.f;
#pragma unroll
  for (int r = 0; r < NREP; r++) s += base[r * REP + idx];
  return s;
}

// A-frag slot for element w1[o][c] (o<192, c<32), 16x16x32 MFMA:
// lane = (c>>3)*16 + (o&15), j = c&7  ->  slot = (o>>4)*512 + lane*8 + j
__device__ __host__ __forceinline__ int afrag_slot(int o, int c) {
  return (o >> 4) * 512 + (c >> 3) * 128 + (o & 15) * 8 + (c & 7);
}

// G-frag slot: patch value p[c][ij] staged so the SAME array serves as A (m=c,k=ij)
// and B (k=ij,n=c) of MFMA 16x16x32 (A/B slot formulas coincide under m<->n).
__device__ __forceinline__ int gfrag_slot(int c, int ij) {
  const int ks = ij >> 5, il = ij & 31;
  return ks * 1024 + (c >> 4) * 512 + (il >> 3) * 128 + (c & 15) * 8 + (il & 7);
}

// ---------------- K0: transpose s; w1 -> bf16 wb1 (A-frag order), rest -> fp32 wt2 ----------------
// w1 branch: per thread pack 8 contiguous A-frag shorts -> ONE 16B store (was 16 x 2B scalar).
// (single variable under test this round; mapping re-derived as bijective + 16B-aligned)
__global__ __launch_bounds__(256) void k0_transpose(const float* __restrict__ s,
                                                    unsigned short* __restrict__ wb1,
                                                    float* __restrict__ wt2) {
  __shared__ float tile[64][65];
  const int blk = blockIdx.x;            // b*219 + kt
  const int b  = blk / 219;
  const int kt = blk - b * 219;
  const int k0 = kt * 64;
  const int t  = threadIdx.x;
  {
    const int f  = t & 63;
    const int kr = t >> 6;
    const float* sp = s + ((size_t)b * HYPER + k0 + kr) * 64 + f;
#pragma unroll
    for (int kk = 0; kk < 16; kk++)
      tile[kr + kk * 4][f] = sp[(size_t)kk * 4 * 64];
  }
  __syncthreads();
  if (kt < 96) {   // w1 region (k < 6144): emit bf16 in A-frag order, 16B per store
    const int f  = t & 63;
    const int c8 = t >> 6;               // 0..3
#pragma unroll
    for (int oi = 0; oi < 2; oi++) {
      const int o = kt * 2 + oi;         // global output channel
      u16x8 v;
#pragma unroll
      for (int j = 0; j < 8; j++)
        v[j] = f2bf(tile[oi * 32 + c8 * 8 + j][f]);   // tile[kk][f], kk = oi*32+c8*8+j
      unsigned short* wp = wb1 + ((size_t)b * 64 + f) * W1SZ
                         + (o >> 4) * 512 + c8 * 128 + (o & 15) * 8;
      *(u16x8*)wp = v;                   // 16B aligned store, = afrag_slot(o, c8*8+j)
    }
  } else {
    const int kk = t & 63;
    const int fr = t >> 6;
    float* wp = wt2 + ((size_t)b * 64 + fr) * WT2SZ + (k0 - W1SZ) + kk;
#pragma unroll
    for (int ff = 0; ff < 16; ff++)
      wp[(size_t)ff * 4 * WT2SZ] = tile[kk][fr + ff * 4];
  }
}

// ---------------- K1: bn1 stats via Gram matrix ----------------
// Sum_ij x1[o]^2 = w1[o]^T G w1[o],  G = P~ P~^T (fp32 from bf16-product MFMA);
// Sum_ij x1[o]   = w1[o] . S,        S = row-sums of P~.
__global__ __launch_bounds__(512) void k1_stats(const float* __restrict__ x,
                                                const unsigned short* __restrict__ wb1,
                                                float* __restrict__ sums) {
  __shared__ __align__(16) unsigned short pG[11 * 1024];   // 22528 B, K padded 324->352
  __shared__ float G[32 * 32];                              // 4096 B
  __shared__ float S[32];
  const int p  = blockIdx.x;
  const int b  = p >> 6;
  const int fi = (p >> 3) & 7;
  const int fj = p & 7;
  const int t  = threadIdx.x;

  // zero the ij-pad region (ij 324..351, all c)
  for (int idx = t; idx < 32 * 28; idx += 512) {
    int c  = idx / 28;
    int ij = 324 + (idx - c * 28);
    pG[gfrag_slot(c, ij)] = 0;
  }
  // gather patch (reflect-pad) into G-frag layout
  const int row0 = fi * 16 - 1, col0 = fj * 16 - 1;
  const float* xb = x + (size_t)b * 32 * 128 * 128;
  for (int idx = t; idx < 32 * A1; idx += 512) {
    int c  = idx / A1;
    int ij = idx - c * A1;
    int ii = ij / 18;
    int jj = ij - ii * 18;
    int r  = row0 + ii; r  = (r  < 0) ? 1 : (r  > 127) ? 126 : r;
    int cl = col0 + jj; cl = (cl < 0) ? 1 : (cl > 127) ? 126 : cl;
    pG[gfrag_slot(c, ij)] = f2bf(xb[((size_t)c * 128 + r) * 128 + cl]);
  }
  __syncthreads();

  const int lane = t & 63;
  const int wv   = t >> 6;           // 0..7
  const int m16  = lane & 15;
  const int quad = lane >> 4;

  if (wv < 4) {
    // wave wv owns G tile (mi,ni); accumulate over 11 K-steps
    const int mi = wv >> 1, ni = wv & 1;
    f32x4 acc = {0.f, 0.f, 0.f, 0.f};
    for (int ks = 0; ks < 11; ks++) {
      bf16x8 a  = *(const bf16x8*)&pG[ks * 1024 + mi * 512 + lane * 8];
      bf16x8 bv = *(const bf16x8*)&pG[ks * 1024 + ni * 512 + lane * 8];
      acc = __builtin_amdgcn_mfma_f32_16x16x32_bf16(a, bv, acc, 0, 0, 0);
    }
#pragma unroll
    for (int r = 0; r < 4; r++)
      G[(mi * 16 + quad * 4 + r) * 32 + ni * 16 + m16] = acc[r];
  } else {
    // waves 4..7: S[c] = sum_ij p~[c][ij]  (8 threads per c)
    const int idx = t - 256;         // 0..255
    const int c   = idx >> 3;
    const int k8  = idx & 7;
    float sv = 0.f;
    for (int ij = k8; ij < A1; ij += 8)
      sv += bf2f(pG[gfrag_slot(c, ij)]);
    sv += __shfl_xor(sv, 1, 64);
    sv += __shfl_xor(sv, 2, 64);
    sv += __shfl_xor(sv, 4, 64);
    if (k8 == 0) S[c] = sv;
  }
  __syncthreads();

  if (t < HID) {
    const int o = t;
    const unsigned short* wp = wb1 + (size_t)p * W1SZ + (o >> 4) * 512 + (o & 15) * 8;
    float w[32];
#pragma unroll
    for (int c8 = 0; c8 < 4; c8++) {
      bf16x8 v = *(const bf16x8*)(wp + c8 * 128);
#pragma unroll
      for (int j = 0; j < 8; j++)
        w[c8 * 8 + j] = bf2f((unsigned short)v[j]);
    }
    float s1 = 0.f, q1 = 0.f;
#pragma unroll
    for (int c = 0; c < 32; c++) {
      float inner = 0.f;
#pragma unroll
      for (int d4 = 0; d4 < 8; d4++) {
        f32x4 g = *(const f32x4*)&G[c * 32 + d4 * 4];
        inner = fmaf(g[0], w[d4 * 4 + 0], inner);
        inner = fmaf(g[1], w[d4 * 4 + 1], inner);
        inner = fmaf(g[2], w[d4 * 4 + 2], inner);
        inner = fmaf(g[3], w[d4 * 4 + 3], inner);
      }
      q1 = fmaf(w[c], inner, q1);
      s1 = fmaf(w[c], S[c], s1);
    }
    atomicAdd(&sums[(p & (NREP - 1)) * REP + o], s1);
    atomicAdd(&sums[(p & (NREP - 1)) * REP + 192 + o], q1);
  }
}

// ---------------- K2: fused conv1-recompute + bn1 + relu6 + depthwise 3x3 + bn2 stats ----
// Full patch, 12 rounds, 2 barriers/round, 512 threads (8 waves).
__global__ __launch_bounds__(512, 4) void k2_fused(const float* __restrict__ x,
                                                   const unsigned short* __restrict__ wb1,
                                                   const float* __restrict__ wt2,
                                                   const float* __restrict__ sums,
                                                   const float* __restrict__ g1,
                                                   const float* __restrict__ b1,
                                                   unsigned short* __restrict__ x2,
                                                   float* __restrict__ sums_out) {
  __shared__ __align__(16) unsigned short pL[21 * 512];      // 21504 B
  __shared__ __align__(16) unsigned short xc[16 * 328];      // 10496 B [c][ij pad]
  __shared__ __align__(16) unsigned short x2s[256 * 18];     //  9216 B [ij][16 + 2 pad]
  __shared__ float w2L[HID * 9];                             //  6912 B
  __shared__ float sc[HID], sh[HID];                         //  1536 B
  __shared__ float st2[384];                                 //  1536 B => 51200 B total
  const int p  = blockIdx.x;
  const int b  = p >> 6;
  const int fi = (p >> 3) & 7;
  const int fj = p & 7;
  const int t  = threadIdx.x;

  const float inv1 = 1.f / 165888.f;    // 512*324
  if (t < HID) {
    float m   = rsum16(sums, t) * inv1;
    float var = rsum16(sums, 192 + t) * inv1 - m * m;
    float scl = g1[t] * rsqrtf(var + EPS);
    sc[t] = scl;
    sh[t] = b1[t] - m * scl;
  }
  if (t < 384) st2[t] = 0.f;
  {
    const float* wtp = wt2 + (size_t)p * WT2SZ;   // w2 at offset 0, 1728 floats
    for (int i = t; i < HID * 9; i += 512) w2L[i] = wtp[i];
  }

  // stage patch B-frags (full 18x18 halo, reflect-pad gather)
  const int row0 = fi * 16 - 1, col0 = fj * 16 - 1;
  const float* xb = x + (size_t)b * 32 * 128 * 128;
  for (int idx = t; idx < 32 * A1; idx += 512) {
    int c  = idx / A1;
    int ij = idx - c * A1;
    int ii = ij / 18;
    int jj = ij - ii * 18;
    int r  = row0 + ii; r  = (r  < 0) ? 1 : (r  > 127) ? 126 : r;
    int cl = col0 + jj; cl = (cl < 0) ? 1 : (cl > 127) ? 126 : cl;
    int slot = ((ij >> 4) * 4 + (c >> 3)) * 128 + (ij & 15) * 8 + (c & 7);
    pL[slot] = f2bf(xb[((size_t)c * 128 + r) * 128 + cl]);
  }
  __syncthreads();

  const int lane = t & 63;
  const int wv   = t >> 6;           // 0..7
  const int m16  = lane & 15;
  const int quad = lane >> 4;
  // dw coords: t = ihq*128 + cdw*8 + jp
  const int ihq = t >> 7;            // 0..3  (output rows ihq*4 .. ihq*4+3)
  const int cdw = (t >> 3) & 15;     // 0..15 (channel within tile)
  const int jp  = t & 7;             // 0..7  (j-pair)
  const unsigned short* wbp = wb1 + (size_t)p * W1SZ;
  unsigned short* x2base = x2 + (size_t)p * 49152;

  // ---- conv1 for one o-tile rt -> xc[c][ij] (bn1+relu6 applied) ----
  auto conv1 = [&](int rt) {
    bf16x8 a = *(const bf16x8*)(wbp + rt * 512 + lane * 8);
    float scv[4], shv[4];
#pragma unroll
    for (int r = 0; r < 4; r++) {
      scv[r] = sc[rt * 16 + quad * 4 + r];
      shv[r] = sh[rt * 16 + quad * 4 + r];
    }
    for (int jt = wv; jt < 21; jt += 8) {
      bf16x8 bb = *(const bf16x8*)&pL[jt * 512 + lane * 8];
      f32x4 d = __builtin_amdgcn_mfma_f32_16x16x32_bf16(a, bb, (f32x4){0.f, 0.f, 0.f, 0.f}, 0, 0, 0);
      const int ij = jt * 16 + m16;
      if (ij < A1) {
#pragma unroll
        for (int r = 0; r < 4; r++) {
          float v = relu6f(fmaf(d[r], scv[r], shv[r]));
          unsigned int u;
          asm("v_cvt_pk_bf16_f32 %0, %1, %2" : "=v"(u) : "v"(v), "v"(v));
          xc[(quad * 4 + r) * 328 + ij] = (unsigned short)u;
        }
      }
    }
  };

  conv1(0);
  __syncthreads();

  for (int rt = 0; rt < 12; rt++) {
    // ---- depthwise on tile rt: thread = (ihq, cdw, jp); aligned b32 LDS reads ----
    {
      const int ch = rt * 16 + cdw;
      float wr[9];
#pragma unroll
      for (int u = 0; u < 9; u++) wr[u] = w2L[ch * 9 + u];
      float a0[4], a1[4];
#pragma unroll
      for (int i = 0; i < 4; i++) { a0[i] = 0.f; a1[i] = 0.f; }
      const unsigned short* xcc = &xc[cdw * 328];
#pragma unroll
      for (int rr = 0; rr < 6; rr++) {
        const int rg = ihq * 4 + rr;
        unsigned int d0 = *(const unsigned int*)&xcc[rg * 18 + jp * 2];
        unsigned int d1 = *(const unsigned int*)&xcc[rg * 18 + jp * 2 + 2];
        float v0 = bf2f(d0 & 0xFFFFu), v1 = bf2f(d0 >> 16);
        float v2 = bf2f(d1 & 0xFFFFu), v3 = bf2f(d1 >> 16);
#pragma unroll
        for (int u = 0; u < 3; u++) {
          int il = rr - u;
          if (il >= 0 && il < 4) {
            a0[il] = fmaf(v0, wr[u * 3 + 0], fmaf(v1, wr[u * 3 + 1], fmaf(v2, wr[u * 3 + 2], a0[il])));
            a1[il] = fmaf(v1, wr[u * 3 + 0], fmaf(v2, wr[u * 3 + 1], fmaf(v3, wr[u * 3 + 2], a1[il])));
          }
        }
      }
      // ---- pack (RNE via cvt_pk), stats on rounded values, transpose to x2s ----
      float ls = 0.f, lq = 0.f;
#pragma unroll
      for (int il = 0; il < 4; il++) {
        const int ig = ihq * 4 + il;
        const int j0 = jp * 2;
        unsigned int ua;
        asm("v_cvt_pk_bf16_f32 %0, %1, %2" : "=v"(ua) : "v"(a0[il]), "v"(a1[il]));
        float s0 = __uint_as_float(ua << 16);
        float s1 = __uint_as_float(ua & 0xFFFF0000u);
        ls += s0 + s1;
        lq = fmaf(s0, s0, fmaf(s1, s1, lq));
        x2s[(ig * 16 + j0) * 18 + cdw]     = (unsigned short)ua;
        x2s[(ig * 16 + j0 + 1) * 18 + cdw] = (unsigned short)(ua >> 16);
      }
      // reduce over jp (lane bits 0..2)
      ls += __shfl_xor(ls, 1, 64); lq += __shfl_xor(lq, 1, 64);
      ls += __shfl_xor(ls, 2, 64); lq += __shfl_xor(lq, 2, 64);
      ls += __shfl_xor(ls, 4, 64); lq += __shfl_xor(lq, 4, 64);
      if (jp == 0) {
        atomicAdd(&st2[ch], ls);
        atomicAdd(&st2[192 + ch], lq);
      }
    }
    __syncthreads();
    // ---- coop store x2s -> global [rt][256][16]; overlap conv1 of next tile ----
    {
      unsigned short* dst = x2base + (size_t)rt * 4096;
#pragma unroll
      for (int k = 0; k < 2; k++) {
        int g  = (k * 512 + t) * 4;          // ushort offset, multiple of 4
        int ij = g >> 4, c0 = g & 15;
        unsigned int v0 = *(const unsigned int*)&x2s[ij * 18 + c0];
        unsigned int v1 = *(const unsigned int*)&x2s[ij * 18 + c0 + 2];
        uint2 v; v.x = v0; v.y = v1;
        *(uint2*)&dst[g] = v;
      }
    }
    if (rt < 11) conv1(rt + 1);
    __syncthreads();
  }
  // bn2 stats -> replica (p mod NREP), offset 384 within replica
  for (int i = t; i < 384; i += 512)
    atomicAdd(&sums_out[(p & (NREP - 1)) * REP + 384 + i], st2[i]);
}

// ---------------- K3: MFMA pointwise 192->32, bn2+relu6 fused on B-load ----------------
// grid: 1024 = patch(512) * ij-half(2). EXACT R8-passing form (plain launch_bounds(256);
// the (256,4) min-waves variant is blacklisted: 2x miscompile signature R9/R10).
__global__ __launch_bounds__(256) void k3_pw2(const unsigned short* __restrict__ x2,
                                              const float* __restrict__ wt2,
                                              const float* __restrict__ sums,
                                              const float* __restrict__ g2,
                                              const float* __restrict__ b2,
                                              unsigned short* __restrict__ x3,
                                              float* __restrict__ sums_out) {
  __shared__ __align__(16) unsigned short wA[12 * 512];   // A frags: [ot(2)][ks(6)]
  __shared__ float sc[HID], sh[HID];
  __shared__ float st3[64];
  const int blk  = blockIdx.x;
  const int p    = blk >> 1;
  const int half = blk & 1;
  const int t    = threadIdx.x;
  const float inv = 1.f / 131072.f;   // 512*256
  for (int c = t; c < HID; c += 256) {
    float m   = rsum16(sums, 384 + c) * inv;
    float var = rsum16(sums, 576 + c) * inv - m * m;
    float scl = g2[c] * rsqrtf(var + EPS);
    sc[c] = scl;
    sh[c] = b2[c] - m * scl;
  }
  if (t < 64) st3[t] = 0.f;
  // stage w3 -> bf16 A-frags: A[m=o&15][k], frag (ot=o>>4, ks=c>>5)
  const float* w3p = wt2 + (size_t)p * WT2SZ + R3OFF;     // [o][192]
  for (int idx = t; idx < 32 * 48; idx += 256) {
    int o  = idx / 48;
    int c4 = idx - o * 48;
    float4 v = *(const float4*)&w3p[o * HID + c4 * 4];
    int slot = ((o >> 4) * 6 + (c4 >> 3)) * 512 + ((((c4 >> 1) & 3) * 16) + (o & 15)) * 8 + (c4 & 1) * 4;
    ushort4 u;
    u.x = f2bf(v.x); u.y = f2bf(v.y); u.z = f2bf(v.z); u.w = f2bf(v.w);
    *(ushort4*)&wA[slot] = u;
  }
  __syncthreads();
  const int lane = t & 63;
  const int wv   = t >> 6;
  const int m16  = lane & 15;
  const int kg   = lane >> 4;
  bf16x8 aF[2][6];
#pragma unroll
  for (int ot = 0; ot < 2; ot++)
#pragma unroll
    for (int ks = 0; ks < 6; ks++)
      aF[ot][ks] = *(const bf16x8*)&wA[(ot * 6 + ks) * 512 + lane * 8];
  const unsigned short* x2p = x2 + (size_t)p * 12 * 4096;
  f32x4 acc[2][2];
#pragma unroll
  for (int it = 0; it < 2; it++)
#pragma unroll
    for (int ot = 0; ot < 2; ot++)
#pragma unroll
      for (int r = 0; r < 4; r++) acc[it][ot][r] = 0.f;
#pragma unroll
  for (int it = 0; it < 2; it++) {
    const int ijt = half * 8 + wv + it * 4;
    const int ij  = ijt * 16 + m16;
    // x2 [ot12][ij][16]: for k = ks*32 + kg*8 + j, addr = ks*8192 + (kg>>1)*4096 + ij*16 + (kg&1)*8
    const unsigned short* brow = x2p + (size_t)(kg >> 1) * 4096 + (size_t)ij * 16 + (kg & 1) * 8;
#pragma unroll
    for (int ks = 0; ks < 6; ks++) {
      u32x4 uv = *(const u32x4*)&brow[ks * 8192];       // 16B load, 8 bf16
      const float* scp = &sc[ks * 32 + kg * 8];
      const float* shp = &sh[ks * 32 + kg * 8];
      u32x4 pk;
#pragma unroll
      for (int q = 0; q < 4; q++) {
        float ylo = relu6f(fmaf(__uint_as_float(uv[q] << 16),          scp[2 * q],     shp[2 * q]));
        float yhi = relu6f(fmaf(__uint_as_float(uv[q] & 0xFFFF0000u),  scp[2 * q + 1], shp[2 * q + 1]));
        unsigned int r;
        asm("v_cvt_pk_bf16_f32 %0, %1, %2" : "=v"(r) : "v"(ylo), "v"(yhi));
        pk[q] = r;
      }
      bf16x8 bb = __builtin_bit_cast(bf16x8, pk);
      acc[it][0] = __builtin_amdgcn_mfma_f32_16x16x32_bf16(aF[0][ks], bb, acc[it][0], 0, 0, 0);
      acc[it][1] = __builtin_amdgcn_mfma_f32_16x16x32_bf16(aF[1][ks], bb, acc[it][1], 0, 0, 0);
    }
  }
  unsigned short* x3p = x3 + (size_t)p * 32 * A2;
  float sacc[2][4] = {{0.f}}, qacc[2][4] = {{0.f}};
#pragma unroll
  for (int it = 0; it < 2; it++) {
    const int ijt = half * 8 + wv + it * 4;
#pragma unroll
    for (int ot = 0; ot < 2; ot++) {
#pragma unroll
      for (int rp = 0; rp < 2; rp++) {
        unsigned int ua;
        asm("v_cvt_pk_bf16_f32 %0, %1, %2" : "=v"(ua)
            : "v"(acc[it][ot][2 * rp]), "v"(acc[it][ot][2 * rp + 1]));
        float v0 = __uint_as_float(ua << 16);
        float v1 = __uint_as_float(ua & 0xFFFF0000u);
        x3p[(size_t)(ot * 16 + kg * 4 + 2 * rp) * A2 + ijt * 16 + m16]     = (unsigned short)ua;
        x3p[(size_t)(ot * 16 + kg * 4 + 2 * rp + 1) * A2 + ijt * 16 + m16] = (unsigned short)(ua >> 16);
        sacc[ot][2 * rp]     += v0;
        sacc[ot][2 * rp + 1] += v1;
        qacc[ot][2 * rp]      = fmaf(v0, v0, qacc[ot][2 * rp]);
        qacc[ot][2 * rp + 1]  = fmaf(v1, v1, qacc[ot][2 * rp + 1]);
      }
    }
  }
#pragma unroll
  for (int ot = 0; ot < 2; ot++)
#pragma unroll
    for (int r = 0; r < 4; r++) {
      float sv = sacc[ot][r], qv = qacc[ot][r];
#pragma unroll
      for (int msk = 1; msk < 16; msk <<= 1) {
        sv += __shfl_xor(sv, msk, 64);
        qv += __shfl_xor(qv, msk, 64);
      }
      if (m16 == 0) {
        int o = ot * 16 + kg * 4 + r;
        atomicAdd(&st3[o], sv);
        atomicAdd(&st3[32 + o], qv);
      }
    }
  __syncthreads();
  if (t < 64) atomicAdd(&sums_out[(blk & (NREP - 1)) * REP + 768 + t], st3[t]);
}

// ---------------- K4: bn3 + residual + layout transform ----------------
__global__ __launch_bounds__(256) void k4_out(const float* __restrict__ x,
                                              const unsigned short* __restrict__ x3,
                                              const float* __restrict__ sums,
                                              const float* __restrict__ g3,
                                              const float* __restrict__ b3,
                                              float* __restrict__ out) {
  const int idx4 = blockIdx.x * 256 + threadIdx.x;   // 1,048,576 float4 total
  const int w4 = idx4 & 31;
  int tmp = idx4 >> 5;
  const int h = tmp & 127; tmp >>= 7;
  const int o = tmp & 31;
  const int b = tmp >> 5;
  const int fi = h >> 4, i = h & 15;
  const int fj = w4 >> 2;
  const int j0 = (w4 & 3) * 4;
  const int p   = b * 64 + fi * 8 + fj;
  const int ij0 = i * 16 + j0;
  const float inv = 1.f / 131072.f;
  float m   = rsum16(sums, 768 + o) * inv;
  float var = rsum16(sums, 800 + o) * inv - m * m;
  float sv  = g3[o] * rsqrtf(var + EPS);
  float shv = b3[o] - m * sv;
  float4 xv = *(const float4*)&x[(size_t)idx4 * 4];
  ushort4 u = *(const ushort4*)&x3[((size_t)p * 32 + o) * A2 + ij0];
  float4 r;
  r.x = fmaf(bf2f(u.x), sv, shv) + xv.x;
  r.y = fmaf(bf2f(u.y), sv, shv) + xv.y;
  r.z = fmaf(bf2f(u.z), sv, shv) + xv.z;
  r.w = fmaf(bf2f(u.w), sv, shv) + xv.w;
  *(float4*)&out[(size_t)idx4 * 4] = r;
}

extern "C" void kernel_launch(void* const* d_in, const int* in_sizes, int n_in,
                              void* d_out, int out_size, void* d_ws, size_t ws_size,
                              hipStream_t stream) {
  const float* x  = (const float*)d_in[0];
  const float* s  = (const float*)d_in[1];
  const float* g1 = (const float*)d_in[2];
  const float* b1 = (const float*)d_in[3];
  const float* g2 = (const float*)d_in[4];
  const float* b2 = (const float*)d_in[5];
  const float* g3 = (const float*)d_in[6];
  const float* b3 = (const float*)d_in[7];
  char* base = (char*)d_ws;
  unsigned short* wb1  = (unsigned short*)(base + WB1_B);
  float*          wt2  = (float*)(base + WT2_B);
  unsigned short* x2   = (unsigned short*)(base + X2_B);
  unsigned short* x3   = (unsigned short*)(base + X3_B);
  float*          sums = (float*)(base + SUM_B);
  float* out = (float*)d_out;

  hipMemsetAsync(sums, 0, NREP * REP * sizeof(float), stream);
  k0_transpose<<<8 * 219, 256, 0, stream>>>(s, wb1, wt2);
  k1_stats<<<P_TOT, 512, 0, stream>>>(x, wb1, sums);
  k2_fused<<<P_TOT, 512, 0, stream>>>(x, wb1, wt2, sums, g1, b1, x2, sums);
  k3_pw2<<<1024, 256, 0, stream>>>(x2, wt2, sums, g2, b2, x3, sums);
  k4_out<<<4096, 256, 0, stream>>>(x, x3, sums, g3, b3, out);
}

// Round 12
// 182.417 us; speedup vs baseline: 1.0029x; 1.0029x over previous
//
#include <hip/hip_runtime.h>

#define EPS 1e-5f

namespace {
constexpr int HYPER = 14016;
constexpr int HID   = 192;
constexpr int A1    = 324;   // 18*18
constexpr int A2    = 256;   // 16*16
constexpr int P_TOT = 512;
constexpr int W1SZ  = 6144;  // 32*192
constexpr int WT2SZ = 7872;  // w2 (1728) + w3 (6144)
constexpr int R3OFF = 1728;  // w3 offset inside wt2

// workspace byte offsets
constexpr size_t WB1_B = 0;                       // bf16 w1 A-frag order [p][6144], 6,291,456 B
constexpr size_t WT2_B = 6291456;                 // fp32 w2+w3 [p][7872], 16,121,856 B
constexpr size_t X2_B  = WT2_B + 16121856;        // bf16 x2 [p][12][256][16], 50,331,648 B
constexpr size_t X3_B  = X2_B + 50331648;         // bf16 x3 [p][32][256], 8,388,608 B
constexpr size_t SUM_B = X3_B + 8388608;          // fp32 16 replicas x 832 floats
// per replica: [0:192) s1 [192:384) q1 [384:576) s2 [576:768) q2 [768:800) s3 [800:832) q3
constexpr int REP  = 832;                         // floats per replica
constexpr int NREP = 16;
}

typedef __attribute__((ext_vector_type(8))) short bf16x8;
typedef __attribute__((ext_vector_type(8))) unsigned short u16x8;
typedef __attribute__((ext_vector_type(4))) float f32x4;
typedef __attribute__((ext_vector_type(4))) unsigned int u32x4;

__device__ __forceinline__ float relu6f(float v) { return fminf(fmaxf(v, 0.f), 6.f); }

__device__ __forceinline__ float bf2f(unsigned int h) {
  return __uint_as_float(h << 16);
}
__device__ __forceinline__ unsigned short f2bf(float f) {
  unsigned int u = __float_as_uint(f);
  return (unsigned short)((u + 0x7FFFu + ((u >> 16) & 1u)) >> 16);
}

// sum the NREP replicas of a stats slot
__device__ __forceinline__ float rsum16(const float* __restrict__ base, int idx) {
  float s = 0.f;
#pragma unroll
  for (int r = 0; r < NREP; r++) s += base[r * REP + idx];
  return s;
}

// A-frag slot for element w1[o][c] (o<192, c<32), 16x16x32 MFMA:
// lane = (c>>3)*16 + (o&15), j = c&7  ->  slot = (o>>4)*512 + lane*8 + j
__device__ __host__ __forceinline__ int afrag_slot(int o, int c) {
  return (o >> 4) * 512 + (c >> 3) * 128 + (o & 15) * 8 + (c & 7);
}

// G-frag slot: patch value p[c][ij] staged so the SAME array serves as A (m=c,k=ij)
// and B (k=ij,n=c) of MFMA 16x16x32 (A/B slot formulas coincide under m<->n).
__device__ __forceinline__ int gfrag_slot(int c, int ij) {
  const int ks = ij >> 5, il = ij & 31;
  return ks * 1024 + (c >> 4) * 512 + (il >> 3) * 128 + (c & 15) * 8 + (il & 7);
}

// ---------------- K0: transpose s; w1 -> bf16 wb1 (A-frag order), rest -> fp32 wt2 ----------------
// w1 branch: per thread pack 8 contiguous A-frag shorts -> ONE 16B store (R11-verified).
__global__ __launch_bounds__(256) void k0_transpose(const float* __restrict__ s,
                                                    unsigned short* __restrict__ wb1,
                                                    float* __restrict__ wt2) {
  __shared__ float tile[64][65];
  const int blk = blockIdx.x;            // b*219 + kt
  const int b  = blk / 219;
  const int kt = blk - b * 219;
  const int k0 = kt * 64;
  const int t  = threadIdx.x;
  {
    const int f  = t & 63;
    const int kr = t >> 6;
    const float* sp = s + ((size_t)b * HYPER + k0 + kr) * 64 + f;
#pragma unroll
    for (int kk = 0; kk < 16; kk++)
      tile[kr + kk * 4][f] = sp[(size_t)kk * 4 * 64];
  }
  __syncthreads();
  if (kt < 96) {   // w1 region (k < 6144): emit bf16 in A-frag order, 16B per store
    const int f  = t & 63;
    const int c8 = t >> 6;               // 0..3
#pragma unroll
    for (int oi = 0; oi < 2; oi++) {
      const int o = kt * 2 + oi;         // global output channel
      u16x8 v;
#pragma unroll
      for (int j = 0; j < 8; j++)
        v[j] = f2bf(tile[oi * 32 + c8 * 8 + j][f]);   // tile[kk][f], kk = oi*32+c8*8+j
      unsigned short* wp = wb1 + ((size_t)b * 64 + f) * W1SZ
                         + (o >> 4) * 512 + c8 * 128 + (o & 15) * 8;
      *(u16x8*)wp = v;                   // 16B aligned store, = afrag_slot(o, c8*8+j)
    }
  } else {
    const int kk = t & 63;
    const int fr = t >> 6;
    float* wp = wt2 + ((size_t)b * 64 + fr) * WT2SZ + (k0 - W1SZ) + kk;
#pragma unroll
    for (int ff = 0; ff < 16; ff++)
      wp[(size_t)ff * 4 * WT2SZ] = tile[kk][fr + ff * 4];
  }
}

// ---------------- K1: bn1 stats via Gram matrix ----------------
// Sum_ij x1[o]^2 = w1[o]^T G w1[o],  G = P~ P~^T (fp32 from bf16-product MFMA);
// Sum_ij x1[o]   = w1[o] . S,        S = row-sums of P~.
__global__ __launch_bounds__(512) void k1_stats(const float* __restrict__ x,
                                                const unsigned short* __restrict__ wb1,
                                                float* __restrict__ sums) {
  __shared__ __align__(16) unsigned short pG[11 * 1024];   // 22528 B, K padded 324->352
  __shared__ float G[32 * 32];                              // 4096 B
  __shared__ float S[32];
  const int p  = blockIdx.x;
  const int b  = p >> 6;
  const int fi = (p >> 3) & 7;
  const int fj = p & 7;
  const int t  = threadIdx.x;

  // zero the ij-pad region (ij 324..351, all c)
  for (int idx = t; idx < 32 * 28; idx += 512) {
    int c  = idx / 28;
    int ij = 324 + (idx - c * 28);
    pG[gfrag_slot(c, ij)] = 0;
  }
  // gather patch (reflect-pad) into G-frag layout
  const int row0 = fi * 16 - 1, col0 = fj * 16 - 1;
  const float* xb = x + (size_t)b * 32 * 128 * 128;
  for (int idx = t; idx < 32 * A1; idx += 512) {
    int c  = idx / A1;
    int ij = idx - c * A1;
    int ii = ij / 18;
    int jj = ij - ii * 18;
    int r  = row0 + ii; r  = (r  < 0) ? 1 : (r  > 127) ? 126 : r;
    int cl = col0 + jj; cl = (cl < 0) ? 1 : (cl > 127) ? 126 : cl;
    pG[gfrag_slot(c, ij)] = f2bf(xb[((size_t)c * 128 + r) * 128 + cl]);
  }
  __syncthreads();

  const int lane = t & 63;
  const int wv   = t >> 6;           // 0..7
  const int m16  = lane & 15;
  const int quad = lane >> 4;

  if (wv < 4) {
    // wave wv owns G tile (mi,ni); accumulate over 11 K-steps
    const int mi = wv >> 1, ni = wv & 1;
    f32x4 acc = {0.f, 0.f, 0.f, 0.f};
    for (int ks = 0; ks < 11; ks++) {
      bf16x8 a  = *(const bf16x8*)&pG[ks * 1024 + mi * 512 + lane * 8];
      bf16x8 bv = *(const bf16x8*)&pG[ks * 1024 + ni * 512 + lane * 8];
      acc = __builtin_amdgcn_mfma_f32_16x16x32_bf16(a, bv, acc, 0, 0, 0);
    }
#pragma unroll
    for (int r = 0; r < 4; r++)
      G[(mi * 16 + quad * 4 + r) * 32 + ni * 16 + m16] = acc[r];
  } else {
    // waves 4..7: S[c] = sum_ij p~[c][ij]  (8 threads per c)
    const int idx = t - 256;         // 0..255
    const int c   = idx >> 3;
    const int k8  = idx & 7;
    float sv = 0.f;
    for (int ij = k8; ij < A1; ij += 8)
      sv += bf2f(pG[gfrag_slot(c, ij)]);
    sv += __shfl_xor(sv, 1, 64);
    sv += __shfl_xor(sv, 2, 64);
    sv += __shfl_xor(sv, 4, 64);
    if (k8 == 0) S[c] = sv;
  }
  __syncthreads();

  if (t < HID) {
    const int o = t;
    const unsigned short* wp = wb1 + (size_t)p * W1SZ + (o >> 4) * 512 + (o & 15) * 8;
    float w[32];
#pragma unroll
    for (int c8 = 0; c8 < 4; c8++) {
      bf16x8 v = *(const bf16x8*)(wp + c8 * 128);
#pragma unroll
      for (int j = 0; j < 8; j++)
        w[c8 * 8 + j] = bf2f((unsigned short)v[j]);
    }
    float s1 = 0.f, q1 = 0.f;
#pragma unroll
    for (int c = 0; c < 32; c++) {
      float inner = 0.f;
#pragma unroll
      for (int d4 = 0; d4 < 8; d4++) {
        f32x4 g = *(const f32x4*)&G[c * 32 + d4 * 4];
        inner = fmaf(g[0], w[d4 * 4 + 0], inner);
        inner = fmaf(g[1], w[d4 * 4 + 1], inner);
        inner = fmaf(g[2], w[d4 * 4 + 2], inner);
        inner = fmaf(g[3], w[d4 * 4 + 3], inner);
      }
      q1 = fmaf(w[c], inner, q1);
      s1 = fmaf(w[c], S[c], s1);
    }
    atomicAdd(&sums[(p & (NREP - 1)) * REP + o], s1);
    atomicAdd(&sums[(p & (NREP - 1)) * REP + 192 + o], q1);
  }
}

// ---------------- K2: fused conv1-recompute + bn1 + relu6 + depthwise 3x3 + bn2 stats ----
// Full patch, 12 rounds, 2 barriers/round, 512 threads (8 waves).
__global__ __launch_bounds__(512, 4) void k2_fused(const float* __restrict__ x,
                                                   const unsigned short* __restrict__ wb1,
                                                   const float* __restrict__ wt2,
                                                   const float* __restrict__ sums,
                                                   const float* __restrict__ g1,
                                                   const float* __restrict__ b1,
                                                   unsigned short* __restrict__ x2,
                                                   float* __restrict__ sums_out) {
  __shared__ __align__(16) unsigned short pL[21 * 512];      // 21504 B
  __shared__ __align__(16) unsigned short xc[16 * 328];      // 10496 B [c][ij pad]
  __shared__ __align__(16) unsigned short x2s[256 * 18];     //  9216 B [ij][16 + 2 pad]
  __shared__ float w2L[HID * 9];                             //  6912 B
  __shared__ float sc[HID], sh[HID];                         //  1536 B
  __shared__ float st2[384];                                 //  1536 B => 51200 B total
  const int p  = blockIdx.x;
  const int b  = p >> 6;
  const int fi = (p >> 3) & 7;
  const int fj = p & 7;
  const int t  = threadIdx.x;

  const float inv1 = 1.f / 165888.f;    // 512*324
  if (t < HID) {
    float m   = rsum16(sums, t) * inv1;
    float var = rsum16(sums, 192 + t) * inv1 - m * m;
    float scl = g1[t] * rsqrtf(var + EPS);
    sc[t] = scl;
    sh[t] = b1[t] - m * scl;
  }
  if (t < 384) st2[t] = 0.f;
  {
    const float* wtp = wt2 + (size_t)p * WT2SZ;   // w2 at offset 0, 1728 floats
    for (int i = t; i < HID * 9; i += 512) w2L[i] = wtp[i];
  }

  // stage patch B-frags (full 18x18 halo, reflect-pad gather)
  const int row0 = fi * 16 - 1, col0 = fj * 16 - 1;
  const float* xb = x + (size_t)b * 32 * 128 * 128;
  for (int idx = t; idx < 32 * A1; idx += 512) {
    int c  = idx / A1;
    int ij = idx - c * A1;
    int ii = ij / 18;
    int jj = ij - ii * 18;
    int r  = row0 + ii; r  = (r  < 0) ? 1 : (r  > 127) ? 126 : r;
    int cl = col0 + jj; cl = (cl < 0) ? 1 : (cl > 127) ? 126 : cl;
    int slot = ((ij >> 4) * 4 + (c >> 3)) * 128 + (ij & 15) * 8 + (c & 7);
    pL[slot] = f2bf(xb[((size_t)c * 128 + r) * 128 + cl]);
  }
  __syncthreads();

  const int lane = t & 63;
  const int wv   = t >> 6;           // 0..7
  const int m16  = lane & 15;
  const int quad = lane >> 4;
  // dw coords: t = ihq*128 + cdw*8 + jp
  const int ihq = t >> 7;            // 0..3  (output rows ihq*4 .. ihq*4+3)
  const int cdw = (t >> 3) & 15;     // 0..15 (channel within tile)
  const int jp  = t & 7;             // 0..7  (j-pair)
  const unsigned short* wbp = wb1 + (size_t)p * W1SZ;
  unsigned short* x2base = x2 + (size_t)p * 49152;

  // ---- conv1 for one o-tile rt -> xc[c][ij] (bn1+relu6 applied) ----
  auto conv1 = [&](int rt) {
    bf16x8 a = *(const bf16x8*)(wbp + rt * 512 + lane * 8);
    float scv[4], shv[4];
#pragma unroll
    for (int r = 0; r < 4; r++) {
      scv[r] = sc[rt * 16 + quad * 4 + r];
      shv[r] = sh[rt * 16 + quad * 4 + r];
    }
    for (int jt = wv; jt < 21; jt += 8) {
      bf16x8 bb = *(const bf16x8*)&pL[jt * 512 + lane * 8];
      f32x4 d = __builtin_amdgcn_mfma_f32_16x16x32_bf16(a, bb, (f32x4){0.f, 0.f, 0.f, 0.f}, 0, 0, 0);
      const int ij = jt * 16 + m16;
      if (ij < A1) {
#pragma unroll
        for (int r = 0; r < 4; r++) {
          float v = relu6f(fmaf(d[r], scv[r], shv[r]));
          unsigned int u;
          asm("v_cvt_pk_bf16_f32 %0, %1, %2" : "=v"(u) : "v"(v), "v"(v));
          xc[(quad * 4 + r) * 328 + ij] = (unsigned short)u;
        }
      }
    }
  };

  conv1(0);
  __syncthreads();

  for (int rt = 0; rt < 12; rt++) {
    // ---- depthwise on tile rt: thread = (ihq, cdw, jp); aligned b32 LDS reads ----
    {
      const int ch = rt * 16 + cdw;
      float wr[9];
#pragma unroll
      for (int u = 0; u < 9; u++) wr[u] = w2L[ch * 9 + u];
      float a0[4], a1[4];
#pragma unroll
      for (int i = 0; i < 4; i++) { a0[i] = 0.f; a1[i] = 0.f; }
      const unsigned short* xcc = &xc[cdw * 328];
#pragma unroll
      for (int rr = 0; rr < 6; rr++) {
        const int rg = ihq * 4 + rr;
        unsigned int d0 = *(const unsigned int*)&xcc[rg * 18 + jp * 2];
        unsigned int d1 = *(const unsigned int*)&xcc[rg * 18 + jp * 2 + 2];
        float v0 = bf2f(d0 & 0xFFFFu), v1 = bf2f(d0 >> 16);
        float v2 = bf2f(d1 & 0xFFFFu), v3 = bf2f(d1 >> 16);
#pragma unroll
        for (int u = 0; u < 3; u++) {
          int il = rr - u;
          if (il >= 0 && il < 4) {
            a0[il] = fmaf(v0, wr[u * 3 + 0], fmaf(v1, wr[u * 3 + 1], fmaf(v2, wr[u * 3 + 2], a0[il])));
            a1[il] = fmaf(v1, wr[u * 3 + 0], fmaf(v2, wr[u * 3 + 1], fmaf(v3, wr[u * 3 + 2], a1[il])));
          }
        }
      }
      // ---- pack (RNE via cvt_pk), stats on rounded values, transpose to x2s ----
      float ls = 0.f, lq = 0.f;
#pragma unroll
      for (int il = 0; il < 4; il++) {
        const int ig = ihq * 4 + il;
        const int j0 = jp * 2;
        unsigned int ua;
        asm("v_cvt_pk_bf16_f32 %0, %1, %2" : "=v"(ua) : "v"(a0[il]), "v"(a1[il]));
        float s0 = __uint_as_float(ua << 16);
        float s1 = __uint_as_float(ua & 0xFFFF0000u);
        ls += s0 + s1;
        lq = fmaf(s0, s0, fmaf(s1, s1, lq));
        x2s[(ig * 16 + j0) * 18 + cdw]     = (unsigned short)ua;
        x2s[(ig * 16 + j0 + 1) * 18 + cdw] = (unsigned short)(ua >> 16);
      }
      // reduce over jp (lane bits 0..2)
      ls += __shfl_xor(ls, 1, 64); lq += __shfl_xor(lq, 1, 64);
      ls += __shfl_xor(ls, 2, 64); lq += __shfl_xor(lq, 2, 64);
      ls += __shfl_xor(ls, 4, 64); lq += __shfl_xor(lq, 4, 64);
      if (jp == 0) {
        atomicAdd(&st2[ch], ls);
        atomicAdd(&st2[192 + ch], lq);
      }
    }
    __syncthreads();
    // ---- coop store x2s -> global [rt][256][16]; overlap conv1 of next tile ----
    {
      unsigned short* dst = x2base + (size_t)rt * 4096;
#pragma unroll
      for (int k = 0; k < 2; k++) {
        int g  = (k * 512 + t) * 4;          // ushort offset, multiple of 4
        int ij = g >> 4, c0 = g & 15;
        unsigned int v0 = *(const unsigned int*)&x2s[ij * 18 + c0];
        unsigned int v1 = *(const unsigned int*)&x2s[ij * 18 + c0 + 2];
        uint2 v; v.x = v0; v.y = v1;
        *(uint2*)&dst[g] = v;
      }
    }
    if (rt < 11) conv1(rt + 1);
    __syncthreads();
  }
  // bn2 stats -> replica (p mod NREP), offset 384 within replica
  for (int i = t; i < 384; i += 512)
    atomicAdd(&sums_out[(p & (NREP - 1)) * REP + 384 + i], st2[i]);
}

// ---------------- K3: MFMA pointwise 192->32, bn2+relu6 fused on B-load ----------------
// grid: 1024 = patch(512) * ij-half(2). Plain launch_bounds(256) ((256,4) blacklisted).
// CHANGE vs R8 body: all 12 x2 loads hoisted into a statically-indexed register array
// BEFORE the dequant+MFMA loop -> forces ~48 VGPR of load data live (allocator must
// provision past its starved 40) and the loads pipeline under vmcnt instead of
// serializing load->use 12 deep. Arithmetic order unchanged (bit-identical).
__global__ __launch_bounds__(256) void k3_pw2(const unsigned short* __restrict__ x2,
                                              const float* __restrict__ wt2,
                                              const float* __restrict__ sums,
                                              const float* __restrict__ g2,
                                              const float* __restrict__ b2,
                                              unsigned short* __restrict__ x3,
                                              float* __restrict__ sums_out) {
  __shared__ __align__(16) unsigned short wA[12 * 512];   // A frags: [ot(2)][ks(6)]
  __shared__ float sc[HID], sh[HID];
  __shared__ float st3[64];
  const int blk  = blockIdx.x;
  const int p    = blk >> 1;
  const int half = blk & 1;
  const int t    = threadIdx.x;
  const float inv = 1.f / 131072.f;   // 512*256
  for (int c = t; c < HID; c += 256) {
    float m   = rsum16(sums, 384 + c) * inv;
    float var = rsum16(sums, 576 + c) * inv - m * m;
    float scl = g2[c] * rsqrtf(var + EPS);
    sc[c] = scl;
    sh[c] = b2[c] - m * scl;
  }
  if (t < 64) st3[t] = 0.f;
  // stage w3 -> bf16 A-frags: A[m=o&15][k], frag (ot=o>>4, ks=c>>5)
  const float* w3p = wt2 + (size_t)p * WT2SZ + R3OFF;     // [o][192]
  for (int idx = t; idx < 32 * 48; idx += 256) {
    int o  = idx / 48;
    int c4 = idx - o * 48;
    float4 v = *(const float4*)&w3p[o * HID + c4 * 4];
    int slot = ((o >> 4) * 6 + (c4 >> 3)) * 512 + ((((c4 >> 1) & 3) * 16) + (o & 15)) * 8 + (c4 & 1) * 4;
    ushort4 u;
    u.x = f2bf(v.x); u.y = f2bf(v.y); u.z = f2bf(v.z); u.w = f2bf(v.w);
    *(ushort4*)&wA[slot] = u;
  }
  __syncthreads();
  const int lane = t & 63;
  const int wv   = t >> 6;
  const int m16  = lane & 15;
  const int kg   = lane >> 4;
  bf16x8 aF[2][6];
#pragma unroll
  for (int ot = 0; ot < 2; ot++)
#pragma unroll
    for (int ks = 0; ks < 6; ks++)
      aF[ot][ks] = *(const bf16x8*)&wA[(ot * 6 + ks) * 512 + lane * 8];
  const unsigned short* x2p = x2 + (size_t)p * 12 * 4096;

  // hoist ALL 12 x2 loads (it x ks) into registers with static indexing
  u32x4 uvv[2][6];
#pragma unroll
  for (int it = 0; it < 2; it++) {
    const int ij = (half * 8 + wv + it * 4) * 16 + m16;
    const unsigned short* brow = x2p + (size_t)(kg >> 1) * 4096 + (size_t)ij * 16 + (kg & 1) * 8;
#pragma unroll
    for (int ks = 0; ks < 6; ks++)
      uvv[it][ks] = *(const u32x4*)&brow[ks * 8192];
  }

  f32x4 acc[2][2];
#pragma unroll
  for (int it = 0; it < 2; it++)
#pragma unroll
    for (int ot = 0; ot < 2; ot++)
#pragma unroll
      for (int r = 0; r < 4; r++) acc[it][ot][r] = 0.f;
#pragma unroll
  for (int it = 0; it < 2; it++) {
#pragma unroll
    for (int ks = 0; ks < 6; ks++) {
      u32x4 uv = uvv[it][ks];
      const float* scp = &sc[ks * 32 + kg * 8];
      const float* shp = &sh[ks * 32 + kg * 8];
      u32x4 pk;
#pragma unroll
      for (int q = 0; q < 4; q++) {
        float ylo = relu6f(fmaf(__uint_as_float(uv[q] << 16),          scp[2 * q],     shp[2 * q]));
        float yhi = relu6f(fmaf(__uint_as_float(uv[q] & 0xFFFF0000u),  scp[2 * q + 1], shp[2 * q + 1]));
        unsigned int r;
        asm("v_cvt_pk_bf16_f32 %0, %1, %2" : "=v"(r) : "v"(ylo), "v"(yhi));
        pk[q] = r;
      }
      bf16x8 bb = __builtin_bit_cast(bf16x8, pk);
      acc[it][0] = __builtin_amdgcn_mfma_f32_16x16x32_bf16(aF[0][ks], bb, acc[it][0], 0, 0, 0);
      acc[it][1] = __builtin_amdgcn_mfma_f32_16x16x32_bf16(aF[1][ks], bb, acc[it][1], 0, 0, 0);
    }
  }
  unsigned short* x3p = x3 + (size_t)p * 32 * A2;
  float sacc[2][4] = {{0.f}}, qacc[2][4] = {{0.f}};
#pragma unroll
  for (int it = 0; it < 2; it++) {
    const int ijt = half * 8 + wv + it * 4;
#pragma unroll
    for (int ot = 0; ot < 2; ot++) {
#pragma unroll
      for (int rp = 0; rp < 2; rp++) {
        unsigned int ua;
        asm("v_cvt_pk_bf16_f32 %0, %1, %2" : "=v"(ua)
            : "v"(acc[it][ot][2 * rp]), "v"(acc[it][ot][2 * rp + 1]));
        float v0 = __uint_as_float(ua << 16);
        float v1 = __uint_as_float(ua & 0xFFFF0000u);
        x3p[(size_t)(ot * 16 + kg * 4 + 2 * rp) * A2 + ijt * 16 + m16]     = (unsigned short)ua;
        x3p[(size_t)(ot * 16 + kg * 4 + 2 * rp + 1) * A2 + ijt * 16 + m16] = (unsigned short)(ua >> 16);
        sacc[ot][2 * rp]     += v0;
        sacc[ot][2 * rp + 1] += v1;
        qacc[ot][2 * rp]      = fmaf(v0, v0, qacc[ot][2 * rp]);
        qacc[ot][2 * rp + 1]  = fmaf(v1, v1, qacc[ot][2 * rp + 1]);
      }
    }
  }
#pragma unroll
  for (int ot = 0; ot < 2; ot++)
#pragma unroll
    for (int r = 0; r < 4; r++) {
      float sv = sacc[ot][r], qv = qacc[ot][r];
#pragma unroll
      for (int msk = 1; msk < 16; msk <<= 1) {
        sv += __shfl_xor(sv, msk, 64);
        qv += __shfl_xor(qv, msk, 64);
      }
      if (m16 == 0) {
        int o = ot * 16 + kg * 4 + r;
        atomicAdd(&st3[o], sv);
        atomicAdd(&st3[32 + o], qv);
      }
    }
  __syncthreads();
  if (t < 64) atomicAdd(&sums_out[(blk & (NREP - 1)) * REP + 768 + t], st3[t]);
}

// ---------------- K4: bn3 + residual + layout transform ----------------
__global__ __launch_bounds__(256) void k4_out(const float* __restrict__ x,
                                              const unsigned short* __restrict__ x3,
                                              const float* __restrict__ sums,
                                              const float* __restrict__ g3,
                                              const float* __restrict__ b3,
                                              float* __restrict__ out) {
  const int idx4 = blockIdx.x * 256 + threadIdx.x;   // 1,048,576 float4 total
  const int w4 = idx4 & 31;
  int tmp = idx4 >> 5;
  const int h = tmp & 127; tmp >>= 7;
  const int o = tmp & 31;
  const int b = tmp >> 5;
  const int fi = h >> 4, i = h & 15;
  const int fj = w4 >> 2;
  const int j0 = (w4 & 3) * 4;
  const int p   = b * 64 + fi * 8 + fj;
  const int ij0 = i * 16 + j0;
  const float inv = 1.f / 131072.f;
  float m   = rsum16(sums, 768 + o) * inv;
  float var = rsum16(sums, 800 + o) * inv - m * m;
  float sv  = g3[o] * rsqrtf(var + EPS);
  float shv = b3[o] - m * sv;
  float4 xv = *(const float4*)&x[(size_t)idx4 * 4];
  ushort4 u = *(const ushort4*)&x3[((size_t)p * 32 + o) * A2 + ij0];
  float4 r;
  r.x = fmaf(bf2f(u.x), sv, shv) + xv.x;
  r.y = fmaf(bf2f(u.y), sv, shv) + xv.y;
  r.z = fmaf(bf2f(u.z), sv, shv) + xv.z;
  r.w = fmaf(bf2f(u.w), sv, shv) + xv.w;
  *(float4*)&out[(size_t)idx4 * 4] = r;
}

extern "C" void kernel_launch(void* const* d_in, const int* in_sizes, int n_in,
                              void* d_out, int out_size, void* d_ws, size_t ws_size,
                              hipStream_t stream) {
  const float* x  = (const float*)d_in[0];
  const float* s  = (const float*)d_in[1];
  const float* g1 = (const float*)d_in[2];
  const float* b1 = (const float*)d_in[3];
  const float* g2 = (const float*)d_in[4];
  const float* b2 = (const float*)d_in[5];
  const float* g3 = (const float*)d_in[6];
  const float* b3 = (const float*)d_in[7];
  char* base = (char*)d_ws;
  unsigned short* wb1  = (unsigned short*)(base + WB1_B);
  float*          wt2  = (float*)(base + WT2_B);
  unsigned short* x2   = (unsigned short*)(base + X2_B);
  unsigned short* x3   = (unsigned short*)(base + X3_B);
  float*          sums = (float*)(base + SUM_B);
  float* out = (float*)d_out;

  hipMemsetAsync(sums, 0, NREP * REP * sizeof(float), stream);
  k0_transpose<<<8 * 219, 256, 0, stream>>>(s, wb1, wt2);
  k1_stats<<<P_TOT, 512, 0, stream>>>(x, wb1, sums);
  k2_fused<<<P_TOT, 512, 0, stream>>>(x, wb1, wt2, sums, g1, b1, x2, sums);
  k3_pw2<<<1024, 256, 0, stream>>>(x2, wt2, sums, g2, b2, x3, sums);
  k4_out<<<4096, 256, 0, stream>>>(x, x3, sums, g3, b3, out);
}

// Round 13
// 180.916 us; speedup vs baseline: 1.0112x; 1.0083x over previous
//
#include <hip/hip_runtime.h>

#define EPS 1e-5f

namespace {
constexpr int HYPER = 14016;
constexpr int HID   = 192;
constexpr int A1    = 324;   // 18*18
constexpr int A2    = 256;   // 16*16
constexpr int P_TOT = 512;
constexpr int W1SZ  = 6144;  // 32*192
constexpr int WT2SZ = 7872;  // w2 (1728) + w3 (6144)
constexpr int R3OFF = 1728;  // w3 offset inside wt2

// workspace byte offsets
constexpr size_t WB1_B = 0;                       // bf16 w1 A-frag order [p][6144], 6,291,456 B
constexpr size_t WT2_B = 6291456;                 // fp32 w2+w3 [p][7872], 16,121,856 B
constexpr size_t X2_B  = WT2_B + 16121856;        // bf16 x2 [p][12][256][16], 50,331,648 B
constexpr size_t X3_B  = X2_B + 50331648;         // bf16 x3 [p][32][256], 8,388,608 B
constexpr size_t SUM_B = X3_B + 8388608;          // fp32 16 replicas x 832 floats
// per replica: [0:192) s1 [192:384) q1 [384:576) s2 [576:768) q2 [768:800) s3 [800:832) q3
constexpr int REP  = 832;                         // floats per replica
constexpr int NREP = 16;
}

typedef __attribute__((ext_vector_type(8))) short bf16x8;
typedef __attribute__((ext_vector_type(8))) unsigned short u16x8;
typedef __attribute__((ext_vector_type(4))) float f32x4;
typedef __attribute__((ext_vector_type(4))) unsigned int u32x4;

__device__ __forceinline__ float relu6f(float v) { return fminf(fmaxf(v, 0.f), 6.f); }

__device__ __forceinline__ float bf2f(unsigned int h) {
  return __uint_as_float(h << 16);
}
__device__ __forceinline__ unsigned short f2bf(float f) {
  unsigned int u = __float_as_uint(f);
  return (unsigned short)((u + 0x7FFFu + ((u >> 16) & 1u)) >> 16);
}

// sum the NREP replicas of a stats slot
__device__ __forceinline__ float rsum16(const float* __restrict__ base, int idx) {
  float s = 0.f;
#pragma unroll
  for (int r = 0; r < NREP; r++) s += base[r * REP + idx];
  return s;
}

// A-frag slot for element w1[o][c] (o<192, c<32), 16x16x32 MFMA:
// lane = (c>>3)*16 + (o&15), j = c&7  ->  slot = (o>>4)*512 + lane*8 + j
__device__ __host__ __forceinline__ int afrag_slot(int o, int c) {
  return (o >> 4) * 512 + (c >> 3) * 128 + (o & 15) * 8 + (c & 7);
}

// G-frag slot: patch value p[c][ij] staged so the SAME array serves as A (m=c,k=ij)
// and B (k=ij,n=c) of MFMA 16x16x32 (A/B slot formulas coincide under m<->n).
__device__ __forceinline__ int gfrag_slot(int c, int ij) {
  const int ks = ij >> 5, il = ij & 31;
  return ks * 1024 + (c >> 4) * 512 + (il >> 3) * 128 + (c & 15) * 8 + (il & 7);
}

// ---------------- K0: transpose s; w1 -> bf16 wb1 (A-frag order), rest -> fp32 wt2 ----------------
// w1 branch: per thread pack 8 contiguous A-frag shorts -> ONE 16B store (R11-verified).
__global__ __launch_bounds__(256) void k0_transpose(const float* __restrict__ s,
                                                    unsigned short* __restrict__ wb1,
                                                    float* __restrict__ wt2) {
  __shared__ float tile[64][65];
  const int blk = blockIdx.x;            // b*219 + kt
  const int b  = blk / 219;
  const int kt = blk - b * 219;
  const int k0 = kt * 64;
  const int t  = threadIdx.x;
  {
    const int f  = t & 63;
    const int kr = t >> 6;
    const float* sp = s + ((size_t)b * HYPER + k0 + kr) * 64 + f;
#pragma unroll
    for (int kk = 0; kk < 16; kk++)
      tile[kr + kk * 4][f] = sp[(size_t)kk * 4 * 64];
  }
  __syncthreads();
  if (kt < 96) {   // w1 region (k < 6144): emit bf16 in A-frag order, 16B per store
    const int f  = t & 63;
    const int c8 = t >> 6;               // 0..3
#pragma unroll
    for (int oi = 0; oi < 2; oi++) {
      const int o = kt * 2 + oi;         // global output channel
      u16x8 v;
#pragma unroll
      for (int j = 0; j < 8; j++)
        v[j] = f2bf(tile[oi * 32 + c8 * 8 + j][f]);   // tile[kk][f], kk = oi*32+c8*8+j
      unsigned short* wp = wb1 + ((size_t)b * 64 + f) * W1SZ
                         + (o >> 4) * 512 + c8 * 128 + (o & 15) * 8;
      *(u16x8*)wp = v;                   // 16B aligned store, = afrag_slot(o, c8*8+j)
    }
  } else {
    const int kk = t & 63;
    const int fr = t >> 6;
    float* wp = wt2 + ((size_t)b * 64 + fr) * WT2SZ + (k0 - W1SZ) + kk;
#pragma unroll
    for (int ff = 0; ff < 16; ff++)
      wp[(size_t)ff * 4 * WT2SZ] = tile[kk][fr + ff * 4];
  }
}

// ---------------- K1: bn1 stats via Gram matrix ----------------
// Sum_ij x1[o]^2 = w1[o]^T G w1[o],  G = P~ P~^T (fp32 from bf16-product MFMA);
// Sum_ij x1[o]   = w1[o] . S,        S = row-sums of P~.
__global__ __launch_bounds__(512) void k1_stats(const float* __restrict__ x,
                                                const unsigned short* __restrict__ wb1,
                                                float* __restrict__ sums) {
  __shared__ __align__(16) unsigned short pG[11 * 1024];   // 22528 B, K padded 324->352
  __shared__ float G[32 * 32];                              // 4096 B
  __shared__ float S[32];
  const int p  = blockIdx.x;
  const int b  = p >> 6;
  const int fi = (p >> 3) & 7;
  const int fj = p & 7;
  const int t  = threadIdx.x;

  // zero the ij-pad region (ij 324..351, all c)
  for (int idx = t; idx < 32 * 28; idx += 512) {
    int c  = idx / 28;
    int ij = 324 + (idx - c * 28);
    pG[gfrag_slot(c, ij)] = 0;
  }
  // gather patch (reflect-pad) into G-frag layout
  const int row0 = fi * 16 - 1, col0 = fj * 16 - 1;
  const float* xb = x + (size_t)b * 32 * 128 * 128;
  for (int idx = t; idx < 32 * A1; idx += 512) {
    int c  = idx / A1;
    int ij = idx - c * A1;
    int ii = ij / 18;
    int jj = ij - ii * 18;
    int r  = row0 + ii; r  = (r  < 0) ? 1 : (r  > 127) ? 126 : r;
    int cl = col0 + jj; cl = (cl < 0) ? 1 : (cl > 127) ? 126 : cl;
    pG[gfrag_slot(c, ij)] = f2bf(xb[((size_t)c * 128 + r) * 128 + cl]);
  }
  __syncthreads();

  const int lane = t & 63;
  const int wv   = t >> 6;           // 0..7
  const int m16  = lane & 15;
  const int quad = lane >> 4;

  if (wv < 4) {
    // wave wv owns G tile (mi,ni); accumulate over 11 K-steps
    const int mi = wv >> 1, ni = wv & 1;
    f32x4 acc = {0.f, 0.f, 0.f, 0.f};
    for (int ks = 0; ks < 11; ks++) {
      bf16x8 a  = *(const bf16x8*)&pG[ks * 1024 + mi * 512 + lane * 8];
      bf16x8 bv = *(const bf16x8*)&pG[ks * 1024 + ni * 512 + lane * 8];
      acc = __builtin_amdgcn_mfma_f32_16x16x32_bf16(a, bv, acc, 0, 0, 0);
    }
#pragma unroll
    for (int r = 0; r < 4; r++)
      G[(mi * 16 + quad * 4 + r) * 32 + ni * 16 + m16] = acc[r];
  } else {
    // waves 4..7: S[c] = sum_ij p~[c][ij]  (8 threads per c)
    const int idx = t - 256;         // 0..255
    const int c   = idx >> 3;
    const int k8  = idx & 7;
    float sv = 0.f;
    for (int ij = k8; ij < A1; ij += 8)
      sv += bf2f(pG[gfrag_slot(c, ij)]);
    sv += __shfl_xor(sv, 1, 64);
    sv += __shfl_xor(sv, 2, 64);
    sv += __shfl_xor(sv, 4, 64);
    if (k8 == 0) S[c] = sv;
  }
  __syncthreads();

  if (t < HID) {
    const int o = t;
    const unsigned short* wp = wb1 + (size_t)p * W1SZ + (o >> 4) * 512 + (o & 15) * 8;
    float w[32];
#pragma unroll
    for (int c8 = 0; c8 < 4; c8++) {
      bf16x8 v = *(const bf16x8*)(wp + c8 * 128);
#pragma unroll
      for (int j = 0; j < 8; j++)
        w[c8 * 8 + j] = bf2f((unsigned short)v[j]);
    }
    float s1 = 0.f, q1 = 0.f;
#pragma unroll
    for (int c = 0; c < 32; c++) {
      float inner = 0.f;
#pragma unroll
      for (int d4 = 0; d4 < 8; d4++) {
        f32x4 g = *(const f32x4*)&G[c * 32 + d4 * 4];
        inner = fmaf(g[0], w[d4 * 4 + 0], inner);
        inner = fmaf(g[1], w[d4 * 4 + 1], inner);
        inner = fmaf(g[2], w[d4 * 4 + 2], inner);
        inner = fmaf(g[3], w[d4 * 4 + 3], inner);
      }
      q1 = fmaf(w[c], inner, q1);
      s1 = fmaf(w[c], S[c], s1);
    }
    atomicAdd(&sums[(p & (NREP - 1)) * REP + o], s1);
    atomicAdd(&sums[(p & (NREP - 1)) * REP + 192 + o], q1);
  }
}

// ---------------- K2: fused conv1-recompute + bn1 + relu6 + depthwise 3x3 + bn2 stats ----
// Full patch, 512 threads (8 waves). NEW: xc and x2s double-buffered -> ONE barrier per
// round (was 2): round rt = { dw(rt): xc[rt&1] -> x2s[rt&1]; coop-store x2s[(rt-1)&1];
// conv1(rt+1) -> xc[(rt+1)&1]; barrier }. 26 -> 14 barriers; dw VALU + conv1 MFMA +
// global store co-issue within one phase. LDS 70912 B (2 blocks/CU unchanged; grid-capped).
__global__ __launch_bounds__(512) void k2_fused(const float* __restrict__ x,
                                                const unsigned short* __restrict__ wb1,
                                                const float* __restrict__ wt2,
                                                const float* __restrict__ sums,
                                                const float* __restrict__ g1,
                                                const float* __restrict__ b1,
                                                unsigned short* __restrict__ x2,
                                                float* __restrict__ sums_out) {
  __shared__ __align__(16) unsigned short pL[21 * 512];       // 21504 B
  __shared__ __align__(16) unsigned short xcD[2][16 * 328];   // 20992 B [buf][c][ij pad]
  __shared__ __align__(16) unsigned short x2sD[2][256 * 18];  // 18432 B [buf][ij][16+2 pad]
  __shared__ float w2L[HID * 9];                              //  6912 B
  __shared__ float sc[HID], sh[HID];                          //  1536 B
  __shared__ float st2[384];                                  //  1536 B => 70912 B total
  const int p  = blockIdx.x;
  const int b  = p >> 6;
  const int fi = (p >> 3) & 7;
  const int fj = p & 7;
  const int t  = threadIdx.x;

  const float inv1 = 1.f / 165888.f;    // 512*324
  if (t < HID) {
    float m   = rsum16(sums, t) * inv1;
    float var = rsum16(sums, 192 + t) * inv1 - m * m;
    float scl = g1[t] * rsqrtf(var + EPS);
    sc[t] = scl;
    sh[t] = b1[t] - m * scl;
  }
  if (t < 384) st2[t] = 0.f;
  {
    const float* wtp = wt2 + (size_t)p * WT2SZ;   // w2 at offset 0, 1728 floats
    for (int i = t; i < HID * 9; i += 512) w2L[i] = wtp[i];
  }

  // stage patch B-frags (full 18x18 halo, reflect-pad gather)
  const int row0 = fi * 16 - 1, col0 = fj * 16 - 1;
  const float* xb = x + (size_t)b * 32 * 128 * 128;
  for (int idx = t; idx < 32 * A1; idx += 512) {
    int c  = idx / A1;
    int ij = idx - c * A1;
    int ii = ij / 18;
    int jj = ij - ii * 18;
    int r  = row0 + ii; r  = (r  < 0) ? 1 : (r  > 127) ? 126 : r;
    int cl = col0 + jj; cl = (cl < 0) ? 1 : (cl > 127) ? 126 : cl;
    int slot = ((ij >> 4) * 4 + (c >> 3)) * 128 + (ij & 15) * 8 + (c & 7);
    pL[slot] = f2bf(xb[((size_t)c * 128 + r) * 128 + cl]);
  }
  __syncthreads();

  const int lane = t & 63;
  const int wv   = t >> 6;           // 0..7
  const int m16  = lane & 15;
  const int quad = lane >> 4;
  // dw coords: t = ihq*128 + cdw*8 + jp
  const int ihq = t >> 7;            // 0..3  (output rows ihq*4 .. ihq*4+3)
  const int cdw = (t >> 3) & 15;     // 0..15 (channel within tile)
  const int jp  = t & 7;             // 0..7  (j-pair)
  const unsigned short* wbp = wb1 + (size_t)p * W1SZ;
  unsigned short* x2base = x2 + (size_t)p * 49152;

  // ---- conv1 for o-tile rt -> xcD[rt&1][c][ij] (bn1+relu6 applied) ----
  auto conv1 = [&](int rt) {
    unsigned short* xc = xcD[rt & 1];
    bf16x8 a = *(const bf16x8*)(wbp + rt * 512 + lane * 8);
    float scv[4], shv[4];
#pragma unroll
    for (int r = 0; r < 4; r++) {
      scv[r] = sc[rt * 16 + quad * 4 + r];
      shv[r] = sh[rt * 16 + quad * 4 + r];
    }
    for (int jt = wv; jt < 21; jt += 8) {
      bf16x8 bb = *(const bf16x8*)&pL[jt * 512 + lane * 8];
      f32x4 d = __builtin_amdgcn_mfma_f32_16x16x32_bf16(a, bb, (f32x4){0.f, 0.f, 0.f, 0.f}, 0, 0, 0);
      const int ij = jt * 16 + m16;
      if (ij < A1) {
#pragma unroll
        for (int r = 0; r < 4; r++) {
          float v = relu6f(fmaf(d[r], scv[r], shv[r]));
          unsigned int u;
          asm("v_cvt_pk_bf16_f32 %0, %1, %2" : "=v"(u) : "v"(v), "v"(v));
          xc[(quad * 4 + r) * 328 + ij] = (unsigned short)u;
        }
      }
    }
  };

  // coop store of a completed x2s buffer -> global tile
  auto storeTile = [&](int rt) {
    const unsigned short* x2s = x2sD[rt & 1];
    unsigned short* dst = x2base + (size_t)rt * 4096;
#pragma unroll
    for (int k = 0; k < 2; k++) {
      int g  = (k * 512 + t) * 4;          // ushort offset, multiple of 4
      int ij = g >> 4, c0 = g & 15;
      unsigned int v0 = *(const unsigned int*)&x2s[ij * 18 + c0];
      unsigned int v1 = *(const unsigned int*)&x2s[ij * 18 + c0 + 2];
      uint2 v; v.x = v0; v.y = v1;
      *(uint2*)&dst[g] = v;
    }
  };

  conv1(0);
  __syncthreads();

  for (int rt = 0; rt < 12; rt++) {
    // ---- depthwise on tile rt: read xcD[rt&1], write x2sD[rt&1] ----
    {
      const unsigned short* xcc = &xcD[rt & 1][cdw * 328];
      unsigned short* x2s = x2sD[rt & 1];
      const int ch = rt * 16 + cdw;
      float wr[9];
#pragma unroll
      for (int u = 0; u < 9; u++) wr[u] = w2L[ch * 9 + u];
      float a0[4], a1[4];
#pragma unroll
      for (int i = 0; i < 4; i++) { a0[i] = 0.f; a1[i] = 0.f; }
#pragma unroll
      for (int rr = 0; rr < 6; rr++) {
        const int rg = ihq * 4 + rr;
        unsigned int d0 = *(const unsigned int*)&xcc[rg * 18 + jp * 2];
        unsigned int d1 = *(const unsigned int*)&xcc[rg * 18 + jp * 2 + 2];
        float v0 = bf2f(d0 & 0xFFFFu), v1 = bf2f(d0 >> 16);
        float v2 = bf2f(d1 & 0xFFFFu), v3 = bf2f(d1 >> 16);
#pragma unroll
        for (int u = 0; u < 3; u++) {
          int il = rr - u;
          if (il >= 0 && il < 4) {
            a0[il] = fmaf(v0, wr[u * 3 + 0], fmaf(v1, wr[u * 3 + 1], fmaf(v2, wr[u * 3 + 2], a0[il])));
            a1[il] = fmaf(v1, wr[u * 3 + 0], fmaf(v2, wr[u * 3 + 1], fmaf(v3, wr[u * 3 + 2], a1[il])));
          }
        }
      }
      // ---- pack (RNE via cvt_pk), stats on rounded values, transpose to x2s ----
      float ls = 0.f, lq = 0.f;
#pragma unroll
      for (int il = 0; il < 4; il++) {
        const int ig = ihq * 4 + il;
        const int j0 = jp * 2;
        unsigned int ua;
        asm("v_cvt_pk_bf16_f32 %0, %1, %2" : "=v"(ua) : "v"(a0[il]), "v"(a1[il]));
        float s0 = __uint_as_float(ua << 16);
        float s1 = __uint_as_float(ua & 0xFFFF0000u);
        ls += s0 + s1;
        lq = fmaf(s0, s0, fmaf(s1, s1, lq));
        x2s[(ig * 16 + j0) * 18 + cdw]     = (unsigned short)ua;
        x2s[(ig * 16 + j0 + 1) * 18 + cdw] = (unsigned short)(ua >> 16);
      }
      // reduce over jp (lane bits 0..2)
      ls += __shfl_xor(ls, 1, 64); lq += __shfl_xor(lq, 1, 64);
      ls += __shfl_xor(ls, 2, 64); lq += __shfl_xor(lq, 2, 64);
      ls += __shfl_xor(ls, 4, 64); lq += __shfl_xor(lq, 4, 64);
      if (jp == 0) {
        atomicAdd(&st2[ch], ls);
        atomicAdd(&st2[192 + ch], lq);
      }
    }
    // ---- coop store PREVIOUS round's x2s (barrier-separated from its dw writes) ----
    if (rt > 0) storeTile(rt - 1);
    // ---- conv1 of next tile into the other xc buffer ----
    if (rt < 11) conv1(rt + 1);
    __syncthreads();
  }
  // final tile store (dw(11) completed before the last barrier)
  storeTile(11);
  // bn2 stats -> replica (p mod NREP), offset 384 within replica
  for (int i = t; i < 384; i += 512)
    atomicAdd(&sums_out[(p & (NREP - 1)) * REP + 384 + i], st2[i]);
}

// ---------------- K3: MFMA pointwise 192->32, bn2+relu6 fused on B-load ----------------
// grid: 1024 = patch(512) * ij-half(2). R12-passing form (plain launch_bounds(256);
// (256,4) blacklisted; hoisted uvv loads kept).
__global__ __launch_bounds__(256) void k3_pw2(const unsigned short* __restrict__ x2,
                                              const float* __restrict__ wt2,
                                              const float* __restrict__ sums,
                                              const float* __restrict__ g2,
                                              const float* __restrict__ b2,
                                              unsigned short* __restrict__ x3,
                                              float* __restrict__ sums_out) {
  __shared__ __align__(16) unsigned short wA[12 * 512];   // A frags: [ot(2)][ks(6)]
  __shared__ float sc[HID], sh[HID];
  __shared__ float st3[64];
  const int blk  = blockIdx.x;
  const int p    = blk >> 1;
  const int half = blk & 1;
  const int t    = threadIdx.x;
  const float inv = 1.f / 131072.f;   // 512*256
  for (int c = t; c < HID; c += 256) {
    float m   = rsum16(sums, 384 + c) * inv;
    float var = rsum16(sums, 576 + c) * inv - m * m;
    float scl = g2[c] * rsqrtf(var + EPS);
    sc[c] = scl;
    sh[c] = b2[c] - m * scl;
  }
  if (t < 64) st3[t] = 0.f;
  // stage w3 -> bf16 A-frags: A[m=o&15][k], frag (ot=o>>4, ks=c>>5)
  const float* w3p = wt2 + (size_t)p * WT2SZ + R3OFF;     // [o][192]
  for (int idx = t; idx < 32 * 48; idx += 256) {
    int o  = idx / 48;
    int c4 = idx - o * 48;
    float4 v = *(const float4*)&w3p[o * HID + c4 * 4];
    int slot = ((o >> 4) * 6 + (c4 >> 3)) * 512 + ((((c4 >> 1) & 3) * 16) + (o & 15)) * 8 + (c4 & 1) * 4;
    ushort4 u;
    u.x = f2bf(v.x); u.y = f2bf(v.y); u.z = f2bf(v.z); u.w = f2bf(v.w);
    *(ushort4*)&wA[slot] = u;
  }
  __syncthreads();
  const int lane = t & 63;
  const int wv   = t >> 6;
  const int m16  = lane & 15;
  const int kg   = lane >> 4;
  bf16x8 aF[2][6];
#pragma unroll
  for (int ot = 0; ot < 2; ot++)
#pragma unroll
    for (int ks = 0; ks < 6; ks++)
      aF[ot][ks] = *(const bf16x8*)&wA[(ot * 6 + ks) * 512 + lane * 8];
  const unsigned short* x2p = x2 + (size_t)p * 12 * 4096;

  // hoist ALL 12 x2 loads (it x ks) into registers with static indexing
  u32x4 uvv[2][6];
#pragma unroll
  for (int it = 0; it < 2; it++) {
    const int ij = (half * 8 + wv + it * 4) * 16 + m16;
    const unsigned short* brow = x2p + (size_t)(kg >> 1) * 4096 + (size_t)ij * 16 + (kg & 1) * 8;
#pragma unroll
    for (int ks = 0; ks < 6; ks++)
      uvv[it][ks] = *(const u32x4*)&brow[ks * 8192];
  }

  f32x4 acc[2][2];
#pragma unroll
  for (int it = 0; it < 2; it++)
#pragma unroll
    for (int ot = 0; ot < 2; ot++)
#pragma unroll
      for (int r = 0; r < 4; r++) acc[it][ot][r] = 0.f;
#pragma unroll
  for (int it = 0; it < 2; it++) {
#pragma unroll
    for (int ks = 0; ks < 6; ks++) {
      u32x4 uv = uvv[it][ks];
      const float* scp = &sc[ks * 32 + kg * 8];
      const float* shp = &sh[ks * 32 + kg * 8];
      u32x4 pk;
#pragma unroll
      for (int q = 0; q < 4; q++) {
        float ylo = relu6f(fmaf(__uint_as_float(uv[q] << 16),          scp[2 * q],     shp[2 * q]));
        float yhi = relu6f(fmaf(__uint_as_float(uv[q] & 0xFFFF0000u),  scp[2 * q + 1], shp[2 * q + 1]));
        unsigned int r;
        asm("v_cvt_pk_bf16_f32 %0, %1, %2" : "=v"(r) : "v"(ylo), "v"(yhi));
        pk[q] = r;
      }
      bf16x8 bb = __builtin_bit_cast(bf16x8, pk);
      acc[it][0] = __builtin_amdgcn_mfma_f32_16x16x32_bf16(aF[0][ks], bb, acc[it][0], 0, 0, 0);
      acc[it][1] = __builtin_amdgcn_mfma_f32_16x16x32_bf16(aF[1][ks], bb, acc[it][1], 0, 0, 0);
    }
  }
  unsigned short* x3p = x3 + (size_t)p * 32 * A2;
  float sacc[2][4] = {{0.f}}, qacc[2][4] = {{0.f}};
#pragma unroll
  for (int it = 0; it < 2; it++) {
    const int ijt = half * 8 + wv + it * 4;
#pragma unroll
    for (int ot = 0; ot < 2; ot++) {
#pragma unroll
      for (int rp = 0; rp < 2; rp++) {
        unsigned int ua;
        asm("v_cvt_pk_bf16_f32 %0, %1, %2" : "=v"(ua)
            : "v"(acc[it][ot][2 * rp]), "v"(acc[it][ot][2 * rp + 1]));
        float v0 = __uint_as_float(ua << 16);
        float v1 = __uint_as_float(ua & 0xFFFF0000u);
        x3p[(size_t)(ot * 16 + kg * 4 + 2 * rp) * A2 + ijt * 16 + m16]     = (unsigned short)ua;
        x3p[(size_t)(ot * 16 + kg * 4 + 2 * rp + 1) * A2 + ijt * 16 + m16] = (unsigned short)(ua >> 16);
        sacc[ot][2 * rp]     += v0;
        sacc[ot][2 * rp + 1] += v1;
        qacc[ot][2 * rp]      = fmaf(v0, v0, qacc[ot][2 * rp]);
        qacc[ot][2 * rp + 1]  = fmaf(v1, v1, qacc[ot][2 * rp + 1]);
      }
    }
  }
#pragma unroll
  for (int ot = 0; ot < 2; ot++)
#pragma unroll
    for (int r = 0; r < 4; r++) {
      float sv = sacc[ot][r], qv = qacc[ot][r];
#pragma unroll
      for (int msk = 1; msk < 16; msk <<= 1) {
        sv += __shfl_xor(sv, msk, 64);
        qv += __shfl_xor(qv, msk, 64);
      }
      if (m16 == 0) {
        int o = ot * 16 + kg * 4 + r;
        atomicAdd(&st3[o], sv);
        atomicAdd(&st3[32 + o], qv);
      }
    }
  __syncthreads();
  if (t < 64) atomicAdd(&sums_out[(blk & (NREP - 1)) * REP + 768 + t], st3[t]);
}

// ---------------- K4: bn3 + residual + layout transform ----------------
__global__ __launch_bounds__(256) void k4_out(const float* __restrict__ x,
                                              const unsigned short* __restrict__ x3,
                                              const float* __restrict__ sums,
                                              const float* __restrict__ g3,
                                              const float* __restrict__ b3,
                                              float* __restrict__ out) {
  const int idx4 = blockIdx.x * 256 + threadIdx.x;   // 1,048,576 float4 total
  const int w4 = idx4 & 31;
  int tmp = idx4 >> 5;
  const int h = tmp & 127; tmp >>= 7;
  const int o = tmp & 31;
  const int b = tmp >> 5;
  const int fi = h >> 4, i = h & 15;
  const int fj = w4 >> 2;
  const int j0 = (w4 & 3) * 4;
  const int p   = b * 64 + fi * 8 + fj;
  const int ij0 = i * 16 + j0;
  const float inv = 1.f / 131072.f;
  float m   = rsum16(sums, 768 + o) * inv;
  float var = rsum16(sums, 800 + o) * inv - m * m;
  float sv  = g3[o] * rsqrtf(var + EPS);
  float shv = b3[o] - m * sv;
  float4 xv = *(const float4*)&x[(size_t)idx4 * 4];
  ushort4 u = *(const ushort4*)&x3[((size_t)p * 32 + o) * A2 + ij0];
  float4 r;
  r.x = fmaf(bf2f(u.x), sv, shv) + xv.x;
  r.y = fmaf(bf2f(u.y), sv, shv) + xv.y;
  r.z = fmaf(bf2f(u.z), sv, shv) + xv.z;
  r.w = fmaf(bf2f(u.w), sv, shv) + xv.w;
  *(float4*)&out[(size_t)idx4 * 4] = r;
}

extern "C" void kernel_launch(void* const* d_in, const int* in_sizes, int n_in,
                              void* d_out, int out_size, void* d_ws, size_t ws_size,
                              hipStream_t stream) {
  const float* x  = (const float*)d_in[0];
  const float* s  = (const float*)d_in[1];
  const float* g1 = (const float*)d_in[2];
  const float* b1 = (const float*)d_in[3];
  const float* g2 = (const float*)d_in[4];
  const float* b2 = (const float*)d_in[5];
  const float* g3 = (const float*)d_in[6];
  const float* b3 = (const float*)d_in[7];
  char* base = (char*)d_ws;
  unsigned short* wb1  = (unsigned short*)(base + WB1_B);
  float*          wt2  = (float*)(base + WT2_B);
  unsigned short* x2   = (unsigned short*)(base + X2_B);
  unsigned short* x3   = (unsigned short*)(base + X3_B);
  float*          sums = (float*)(base + SUM_B);
  float* out = (float*)d_out;

  hipMemsetAsync(sums, 0, NREP * REP * sizeof(float), stream);
  k0_transpose<<<8 * 219, 256, 0, stream>>>(s, wb1, wt2);
  k1_stats<<<P_TOT, 512, 0, stream>>>(x, wb1, sums);
  k2_fused<<<P_TOT, 512, 0, stream>>>(x, wb1, wt2, sums, g1, b1, x2, sums);
  k3_pw2<<<1024, 256, 0, stream>>>(x2, wt2, sums, g2, b2, x3, sums);
  k4_out<<<4096, 256, 0, stream>>>(x, x3, sums, g3, b3, out);
}

// Round 15
// 178.882 us; speedup vs baseline: 1.0227x; 1.0114x over previous
//
#include <hip/hip_runtime.h>

#define EPS 1e-5f

namespace {
constexpr int HYPER = 14016;
constexpr int HID   = 192;
constexpr int A1    = 324;   // 18*18
constexpr int A2    = 256;   // 16*16
constexpr int P_TOT = 512;
constexpr int W1SZ  = 6144;  // 32*192
constexpr int WT2SZ = 7872;  // w2 (1728) + w3 (6144)
constexpr int R3OFF = 1728;  // w3 offset inside wt2

// workspace byte offsets
constexpr size_t WB1_B = 0;                       // bf16 w1 A-frag order [p][6144]
constexpr size_t WT2_B = 6291456;                 // fp32 w2+w3 [p][7872]
constexpr size_t X2_B  = WT2_B + 16121856;        // bf16 x2 [p][12][256][16]
constexpr size_t X3_B  = X2_B + 50331648;         // bf16 x3 [p][32][256]
constexpr size_t SUM_B = X3_B + 8388608;          // fp32 16 replicas x 832 floats
// per replica: [0:192) s1 [192:384) q1 [384:576) s2 [576:768) q2 [768:800) s3 [800:832) q3
constexpr int REP  = 832;                         // floats per replica
constexpr int NREP = 16;
}

typedef __attribute__((ext_vector_type(8))) short bf16x8;
typedef __attribute__((ext_vector_type(8))) unsigned short u16x8;
typedef __attribute__((ext_vector_type(4))) float f32x4;
typedef __attribute__((ext_vector_type(4))) unsigned int u32x4;

__device__ __forceinline__ float relu6f(float v) { return fminf(fmaxf(v, 0.f), 6.f); }

__device__ __forceinline__ float bf2f(unsigned int h) {
  return __uint_as_float(h << 16);
}
__device__ __forceinline__ unsigned short f2bf(float f) {
  unsigned int u = __float_as_uint(f);
  return (unsigned short)((u + 0x7FFFu + ((u >> 16) & 1u)) >> 16);
}

// sum the NREP replicas of a stats slot
__device__ __forceinline__ float rsum16(const float* __restrict__ base, int idx) {
  float s = 0.f;
#pragma unroll
  for (int r = 0; r < NREP; r++) s += base[r * REP + idx];
  return s;
}

// A-frag slot for element w1[o][c] (o<192, c<32), 16x16x32 MFMA:
// lane = (c>>3)*16 + (o&15), j = c&7  ->  slot = (o>>4)*512 + lane*8 + j
__device__ __host__ __forceinline__ int afrag_slot(int o, int c) {
  return (o >> 4) * 512 + (c >> 3) * 128 + (o & 15) * 8 + (c & 7);
}

// G-frag slot: patch value p[c][ij] staged so the SAME array serves as A (m=c,k=ij)
// and B (k=ij,n=c) of MFMA 16x16x32 (A/B slot formulas coincide under m<->n).
__device__ __forceinline__ int gfrag_slot(int c, int ij) {
  const int ks = ij >> 5, il = ij & 31;
  return ks * 1024 + (c >> 4) * 512 + (il >> 3) * 128 + (c & 15) * 8 + (il & 7);
}

// ---------------- K0: transpose s; w1 -> bf16 wb1 (A-frag order), rest -> fp32 wt2 ----------------
// w1 branch: 16B packed stores (R11-verified). NEW: blocks 0..15 also zero the sums
// replicas (replaces the hipMemsetAsync dispatch; k1 reads sums only after k0 completes).
__global__ __launch_bounds__(256) void k0_transpose(const float* __restrict__ s,
                                                    unsigned short* __restrict__ wb1,
                                                    float* __restrict__ wt2,
                                                    float* __restrict__ sums) {
  __shared__ float tile[64][65];
  const int blk = blockIdx.x;            // b*219 + kt
  const int b  = blk / 219;
  const int kt = blk - b * 219;
  const int k0 = kt * 64;
  const int t  = threadIdx.x;
  if (blk < NREP) {
    for (int i = t; i < REP; i += 256) sums[blk * REP + i] = 0.f;
  }
  {
    const int f  = t & 63;
    const int kr = t >> 6;
    const float* sp = s + ((size_t)b * HYPER + k0 + kr) * 64 + f;
#pragma unroll
    for (int kk = 0; kk < 16; kk++)
      tile[kr + kk * 4][f] = sp[(size_t)kk * 4 * 64];
  }
  __syncthreads();
  if (kt < 96) {   // w1 region (k < 6144): emit bf16 in A-frag order, 16B per store
    const int f  = t & 63;
    const int c8 = t >> 6;               // 0..3
#pragma unroll
    for (int oi = 0; oi < 2; oi++) {
      const int o = kt * 2 + oi;         // global output channel
      u16x8 v;
#pragma unroll
      for (int j = 0; j < 8; j++)
        v[j] = f2bf(tile[oi * 32 + c8 * 8 + j][f]);   // tile[kk][f], kk = oi*32+c8*8+j
      unsigned short* wp = wb1 + ((size_t)b * 64 + f) * W1SZ
                         + (o >> 4) * 512 + c8 * 128 + (o & 15) * 8;
      *(u16x8*)wp = v;                   // 16B aligned store, = afrag_slot(o, c8*8+j)
    }
  } else {
    const int kk = t & 63;
    const int fr = t >> 6;
    float* wp = wt2 + ((size_t)b * 64 + fr) * WT2SZ + (k0 - W1SZ) + kk;
#pragma unroll
    for (int ff = 0; ff < 16; ff++)
      wp[(size_t)ff * 4 * WT2SZ] = tile[kk][fr + ff * 4];
  }
}

// ---------------- K1: bn1 stats via Gram matrix ----------------
// Sum_ij x1[o]^2 = w1[o]^T G w1[o],  G = P~ P~^T (fp32 from bf16-product MFMA);
// Sum_ij x1[o]   = w1[o] . S,        S = row-sums of P~.
__global__ __launch_bounds__(512) void k1_stats(const float* __restrict__ x,
                                                const unsigned short* __restrict__ wb1,
                                                float* __restrict__ sums) {
  __shared__ __align__(16) unsigned short pG[11 * 1024];   // 22528 B, K padded 324->352
  __shared__ float G[32 * 32];                              // 4096 B
  __shared__ float S[32];
  const int p  = blockIdx.x;
  const int b  = p >> 6;
  const int fi = (p >> 3) & 7;
  const int fj = p & 7;
  const int t  = threadIdx.x;

  // zero the ij-pad region (ij 324..351, all c)
  for (int idx = t; idx < 32 * 28; idx += 512) {
    int c  = idx / 28;
    int ij = 324 + (idx - c * 28);
    pG[gfrag_slot(c, ij)] = 0;
  }
  // gather patch (reflect-pad) into G-frag layout
  const int row0 = fi * 16 - 1, col0 = fj * 16 - 1;
  const float* xb = x + (size_t)b * 32 * 128 * 128;
  for (int idx = t; idx < 32 * A1; idx += 512) {
    int c  = idx / A1;
    int ij = idx - c * A1;
    int ii = ij / 18;
    int jj = ij - ii * 18;
    int r  = row0 + ii; r  = (r  < 0) ? 1 : (r  > 127) ? 126 : r;
    int cl = col0 + jj; cl = (cl < 0) ? 1 : (cl > 127) ? 126 : cl;
    pG[gfrag_slot(c, ij)] = f2bf(xb[((size_t)c * 128 + r) * 128 + cl]);
  }
  __syncthreads();

  const int lane = t & 63;
  const int wv   = t >> 6;           // 0..7
  const int m16  = lane & 15;
  const int quad = lane >> 4;

  if (wv < 4) {
    // wave wv owns G tile (mi,ni); accumulate over 11 K-steps
    const int mi = wv >> 1, ni = wv & 1;
    f32x4 acc = {0.f, 0.f, 0.f, 0.f};
    for (int ks = 0; ks < 11; ks++) {
      bf16x8 a  = *(const bf16x8*)&pG[ks * 1024 + mi * 512 + lane * 8];
      bf16x8 bv = *(const bf16x8*)&pG[ks * 1024 + ni * 512 + lane * 8];
      acc = __builtin_amdgcn_mfma_f32_16x16x32_bf16(a, bv, acc, 0, 0, 0);
    }
#pragma unroll
    for (int r = 0; r < 4; r++)
      G[(mi * 16 + quad * 4 + r) * 32 + ni * 16 + m16] = acc[r];
  } else {
    // waves 4..7: S[c] = sum_ij p~[c][ij]  (8 threads per c)
    const int idx = t - 256;         // 0..255
    const int c   = idx >> 3;
    const int k8  = idx & 7;
    float sv = 0.f;
    for (int ij = k8; ij < A1; ij += 8)
      sv += bf2f(pG[gfrag_slot(c, ij)]);
    sv += __shfl_xor(sv, 1, 64);
    sv += __shfl_xor(sv, 2, 64);
    sv += __shfl_xor(sv, 4, 64);
    if (k8 == 0) S[c] = sv;
  }
  __syncthreads();

  if (t < HID) {
    const int o = t;
    const unsigned short* wp = wb1 + (size_t)p * W1SZ + (o >> 4) * 512 + (o & 15) * 8;
    float w[32];
#pragma unroll
    for (int c8 = 0; c8 < 4; c8++) {
      bf16x8 v = *(const bf16x8*)(wp + c8 * 128);
#pragma unroll
      for (int j = 0; j < 8; j++)
        w[c8 * 8 + j] = bf2f((unsigned short)v[j]);
    }
    float s1 = 0.f, q1 = 0.f;
#pragma unroll
    for (int c = 0; c < 32; c++) {
      float inner = 0.f;
#pragma unroll
      for (int d4 = 0; d4 < 8; d4++) {
        f32x4 g = *(const f32x4*)&G[c * 32 + d4 * 4];
        inner = fmaf(g[0], w[d4 * 4 + 0], inner);
        inner = fmaf(g[1], w[d4 * 4 + 1], inner);
        inner = fmaf(g[2], w[d4 * 4 + 2], inner);
        inner = fmaf(g[3], w[d4 * 4 + 3], inner);
      }
      q1 = fmaf(w[c], inner, q1);
      s1 = fmaf(w[c], S[c], s1);
    }
    atomicAdd(&sums[(p & (NREP - 1)) * REP + o], s1);
    atomicAdd(&sums[(p & (NREP - 1)) * REP + 192 + o], q1);
  }
}

// ---------------- K2: fused conv1-recompute + bn1 + relu6 + depthwise 3x3 + bn2 stats ----
// Full patch, 512 threads (8 waves), double-buffered xc/x2s, one barrier per round.
__global__ __launch_bounds__(512) void k2_fused(const float* __restrict__ x,
                                                const unsigned short* __restrict__ wb1,
                                                const float* __restrict__ wt2,
                                                const float* __restrict__ sums,
                                                const float* __restrict__ g1,
                                                const float* __restrict__ b1,
                                                unsigned short* __restrict__ x2,
                                                float* __restrict__ sums_out) {
  __shared__ __align__(16) unsigned short pL[21 * 512];       // 21504 B
  __shared__ __align__(16) unsigned short xcD[2][16 * 328];   // 20992 B [buf][c][ij pad]
  __shared__ __align__(16) unsigned short x2sD[2][256 * 18];  // 18432 B [buf][ij][16+2 pad]
  __shared__ float w2L[HID * 9];                              //  6912 B
  __shared__ float sc[HID], sh[HID];                          //  1536 B
  __shared__ float st2[384];                                  //  1536 B => 70912 B total
  const int p  = blockIdx.x;
  const int b  = p >> 6;
  const int fi = (p >> 3) & 7;
  const int fj = p & 7;
  const int t  = threadIdx.x;

  const float inv1 = 1.f / 165888.f;    // 512*324
  if (t < HID) {
    float m   = rsum16(sums, t) * inv1;
    float var = rsum16(sums, 192 + t) * inv1 - m * m;
    float scl = g1[t] * rsqrtf(var + EPS);
    sc[t] = scl;
    sh[t] = b1[t] - m * scl;
  }
  if (t < 384) st2[t] = 0.f;
  {
    const float* wtp = wt2 + (size_t)p * WT2SZ;   // w2 at offset 0, 1728 floats
    for (int i = t; i < HID * 9; i += 512) w2L[i] = wtp[i];
  }

  // stage patch B-frags (full 18x18 halo, reflect-pad gather)
  const int row0 = fi * 16 - 1, col0 = fj * 16 - 1;
  const float* xb = x + (size_t)b * 32 * 128 * 128;
  for (int idx = t; idx < 32 * A1; idx += 512) {
    int c  = idx / A1;
    int ij = idx - c * A1;
    int ii = ij / 18;
    int jj = ij - ii * 18;
    int r  = row0 + ii; r  = (r  < 0) ? 1 : (r  > 127) ? 126 : r;
    int cl = col0 + jj; cl = (cl < 0) ? 1 : (cl > 127) ? 126 : cl;
    int slot = ((ij >> 4) * 4 + (c >> 3)) * 128 + (ij & 15) * 8 + (c & 7);
    pL[slot] = f2bf(xb[((size_t)c * 128 + r) * 128 + cl]);
  }
  __syncthreads();

  const int lane = t & 63;
  const int wv   = t >> 6;           // 0..7
  const int m16  = lane & 15;
  const int quad = lane >> 4;
  // dw coords: t = ihq*128 + cdw*8 + jp
  const int ihq = t >> 7;            // 0..3  (output rows ihq*4 .. ihq*4+3)
  const int cdw = (t >> 3) & 15;     // 0..15 (channel within tile)
  const int jp  = t & 7;             // 0..7  (j-pair)
  const unsigned short* wbp = wb1 + (size_t)p * W1SZ;
  unsigned short* x2base = x2 + (size_t)p * 49152;

  // ---- conv1 for o-tile rt -> xcD[rt&1][c][ij] (bn1+relu6 applied) ----
  auto conv1 = [&](int rt) {
    unsigned short* xc = xcD[rt & 1];
    bf16x8 a = *(const bf16x8*)(wbp + rt * 512 + lane * 8);
    float scv[4], shv[4];
#pragma unroll
    for (int r = 0; r < 4; r++) {
      scv[r] = sc[rt * 16 + quad * 4 + r];
      shv[r] = sh[rt * 16 + quad * 4 + r];
    }
    for (int jt = wv; jt < 21; jt += 8) {
      bf16x8 bb = *(const bf16x8*)&pL[jt * 512 + lane * 8];
      f32x4 d = __builtin_amdgcn_mfma_f32_16x16x32_bf16(a, bb, (f32x4){0.f, 0.f, 0.f, 0.f}, 0, 0, 0);
      const int ij = jt * 16 + m16;
      if (ij < A1) {
#pragma unroll
        for (int r = 0; r < 4; r++) {
          float v = relu6f(fmaf(d[r], scv[r], shv[r]));
          unsigned int u;
          asm("v_cvt_pk_bf16_f32 %0, %1, %2" : "=v"(u) : "v"(v), "v"(v));
          xc[(quad * 4 + r) * 328 + ij] = (unsigned short)u;
        }
      }
    }
  };

  // coop store of a completed x2s buffer -> global tile
  auto storeTile = [&](int rt) {
    const unsigned short* x2s = x2sD[rt & 1];
    unsigned short* dst = x2base + (size_t)rt * 4096;
#pragma unroll
    for (int k = 0; k < 2; k++) {
      int g  = (k * 512 + t) * 4;          // ushort offset, multiple of 4
      int ij = g >> 4, c0 = g & 15;
      unsigned int v0 = *(const unsigned int*)&x2s[ij * 18 + c0];
      unsigned int v1 = *(const unsigned int*)&x2s[ij * 18 + c0 + 2];
      uint2 v; v.x = v0; v.y = v1;
      *(uint2*)&dst[g] = v;
    }
  };

  conv1(0);
  __syncthreads();

  for (int rt = 0; rt < 12; rt++) {
    // ---- depthwise on tile rt: read xcD[rt&1], write x2sD[rt&1] ----
    {
      const unsigned short* xcc = &xcD[rt & 1][cdw * 328];
      unsigned short* x2s = x2sD[rt & 1];
      const int ch = rt * 16 + cdw;
      float wr[9];
#pragma unroll
      for (int u = 0; u < 9; u++) wr[u] = w2L[ch * 9 + u];
      float a0[4], a1[4];
#pragma unroll
      for (int i = 0; i < 4; i++) { a0[i] = 0.f; a1[i] = 0.f; }
#pragma unroll
      for (int rr = 0; rr < 6; rr++) {
        const int rg = ihq * 4 + rr;
        unsigned int d0 = *(const unsigned int*)&xcc[rg * 18 + jp * 2];
        unsigned int d1 = *(const unsigned int*)&xcc[rg * 18 + jp * 2 + 2];
        float v0 = bf2f(d0 & 0xFFFFu), v1 = bf2f(d0 >> 16);
        float v2 = bf2f(d1 & 0xFFFFu), v3 = bf2f(d1 >> 16);
#pragma unroll
        for (int u = 0; u < 3; u++) {
          int il = rr - u;
          if (il >= 0 && il < 4) {
            a0[il] = fmaf(v0, wr[u * 3 + 0], fmaf(v1, wr[u * 3 + 1], fmaf(v2, wr[u * 3 + 2], a0[il])));
            a1[il] = fmaf(v1, wr[u * 3 + 0], fmaf(v2, wr[u * 3 + 1], fmaf(v3, wr[u * 3 + 2], a1[il])));
          }
        }
      }
      // ---- pack (RNE via cvt_pk), stats on rounded values, transpose to x2s ----
      float ls = 0.f, lq = 0.f;
#pragma unroll
      for (int il = 0; il < 4; il++) {
        const int ig = ihq * 4 + il;
        const int j0 = jp * 2;
        unsigned int ua;
        asm("v_cvt_pk_bf16_f32 %0, %1, %2" : "=v"(ua) : "v"(a0[il]), "v"(a1[il]));
        float s0 = __uint_as_float(ua << 16);
        float s1 = __uint_as_float(ua & 0xFFFF0000u);
        ls += s0 + s1;
        lq = fmaf(s0, s0, fmaf(s1, s1, lq));
        x2s[(ig * 16 + j0) * 18 + cdw]     = (unsigned short)ua;
        x2s[(ig * 16 + j0 + 1) * 18 + cdw] = (unsigned short)(ua >> 16);
      }
      // reduce over jp (lane bits 0..2)
      ls += __shfl_xor(ls, 1, 64); lq += __shfl_xor(lq, 1, 64);
      ls += __shfl_xor(ls, 2, 64); lq += __shfl_xor(lq, 2, 64);
      ls += __shfl_xor(ls, 4, 64); lq += __shfl_xor(lq, 4, 64);
      if (jp == 0) {
        atomicAdd(&st2[ch], ls);
        atomicAdd(&st2[192 + ch], lq);
      }
    }
    // ---- coop store PREVIOUS round's x2s (barrier-separated from its dw writes) ----
    if (rt > 0) storeTile(rt - 1);
    // ---- conv1 of next tile into the other xc buffer ----
    if (rt < 11) conv1(rt + 1);
    __syncthreads();
  }
  // final tile store (dw(11) completed before the last barrier)
  storeTile(11);
  // bn2 stats -> replica (p mod NREP), offset 384 within replica
  for (int i = t; i < 384; i += 512)
    atomicAdd(&sums_out[(p & (NREP - 1)) * REP + 384 + i], st2[i]);
}

// ---------------- K3: MFMA pointwise 192->32, bn2+relu6 fused on B-load ----------------
// grid: 1024 = patch(512) * ij-half(2). Plain launch_bounds(256) ((256,4) blacklisted);
// hoisted uvv loads (R12-verified).
__global__ __launch_bounds__(256) void k3_pw2(const unsigned short* __restrict__ x2,
                                              const float* __restrict__ wt2,
                                              const float* __restrict__ sums,
                                              const float* __restrict__ g2,
                                              const float* __restrict__ b2,
                                              unsigned short* __restrict__ x3,
                                              float* __restrict__ sums_out) {
  __shared__ __align__(16) unsigned short wA[12 * 512];   // A frags: [ot(2)][ks(6)]
  __shared__ float sc[HID], sh[HID];
  __shared__ float st3[64];
  const int blk  = blockIdx.x;
  const int p    = blk >> 1;
  const int half = blk & 1;
  const int t    = threadIdx.x;
  const float inv = 1.f / 131072.f;   // 512*256
  for (int c = t; c < HID; c += 256) {
    float m   = rsum16(sums, 384 + c) * inv;
    float var = rsum16(sums, 576 + c) * inv - m * m;
    float scl = g2[c] * rsqrtf(var + EPS);
    sc[c] = scl;
    sh[c] = b2[c] - m * scl;
  }
  if (t < 64) st3[t] = 0.f;
  // stage w3 -> bf16 A-frags: A[m=o&15][k], frag (ot=o>>4, ks=c>>5)
  const float* w3p = wt2 + (size_t)p * WT2SZ + R3OFF;     // [o][192]
  for (int idx = t; idx < 32 * 48; idx += 256) {
    int o  = idx / 48;
    int c4 = idx - o * 48;
    float4 v = *(const float4*)&w3p[o * HID + c4 * 4];
    int slot = ((o >> 4) * 6 + (c4 >> 3)) * 512 + ((((c4 >> 1) & 3) * 16) + (o & 15)) * 8 + (c4 & 1) * 4;
    ushort4 u;
    u.x = f2bf(v.x); u.y = f2bf(v.y); u.z = f2bf(v.z); u.w = f2bf(v.w);
    *(ushort4*)&wA[slot] = u;
  }
  __syncthreads();
  const int lane = t & 63;
  const int wv   = t >> 6;
  const int m16  = lane & 15;
  const int kg   = lane >> 4;
  bf16x8 aF[2][6];
#pragma unroll
  for (int ot = 0; ot < 2; ot++)
#pragma unroll
    for (int ks = 0; ks < 6; ks++)
      aF[ot][ks] = *(const bf16x8*)&wA[(ot * 6 + ks) * 512 + lane * 8];
  const unsigned short* x2p = x2 + (size_t)p * 12 * 4096;

  // hoist ALL 12 x2 loads (it x ks) into registers with static indexing
  u32x4 uvv[2][6];
#pragma unroll
  for (int it = 0; it < 2; it++) {
    const int ij = (half * 8 + wv + it * 4) * 16 + m16;
    const unsigned short* brow = x2p + (size_t)(kg >> 1) * 4096 + (size_t)ij * 16 + (kg & 1) * 8;
#pragma unroll
    for (int ks = 0; ks < 6; ks++)
      uvv[it][ks] = *(const u32x4*)&brow[ks * 8192];
  }

  f32x4 acc[2][2];
#pragma unroll
  for (int it = 0; it < 2; it++)
#pragma unroll
    for (int ot = 0; ot < 2; ot++)
#pragma unroll
      for (int r = 0; r < 4; r++) acc[it][ot][r] = 0.f;
#pragma unroll
  for (int it = 0; it < 2; it++) {
#pragma unroll
    for (int ks = 0; ks < 6; ks++) {
      u32x4 uv = uvv[it][ks];
      const float* scp = &sc[ks * 32 + kg * 8];
      const float* shp = &sh[ks * 32 + kg * 8];
      u32x4 pk;
#pragma unroll
      for (int q = 0; q < 4; q++) {
        float ylo = relu6f(fmaf(__uint_as_float(uv[q] << 16),          scp[2 * q],     shp[2 * q]));
        float yhi = relu6f(fmaf(__uint_as_float(uv[q] & 0xFFFF0000u),  scp[2 * q + 1], shp[2 * q + 1]));
        unsigned int r;
        asm("v_cvt_pk_bf16_f32 %0, %1, %2" : "=v"(r) : "v"(ylo), "v"(yhi));
        pk[q] = r;
      }
      bf16x8 bb = __builtin_bit_cast(bf16x8, pk);
      acc[it][0] = __builtin_amdgcn_mfma_f32_16x16x32_bf16(aF[0][ks], bb, acc[it][0], 0, 0, 0);
      acc[it][1] = __builtin_amdgcn_mfma_f32_16x16x32_bf16(aF[1][ks], bb, acc[it][1], 0, 0, 0);
    }
  }
  unsigned short* x3p = x3 + (size_t)p * 32 * A2;
  float sacc[2][4] = {{0.f}}, qacc[2][4] = {{0.f}};
#pragma unroll
  for (int it = 0; it < 2; it++) {
    const int ijt = half * 8 + wv + it * 4;
#pragma unroll
    for (int ot = 0; ot < 2; ot++) {
#pragma unroll
      for (int rp = 0; rp < 2; rp++) {
        unsigned int ua;
        asm("v_cvt_pk_bf16_f32 %0, %1, %2" : "=v"(ua)
            : "v"(acc[it][ot][2 * rp]), "v"(acc[it][ot][2 * rp + 1]));
        float v0 = __uint_as_float(ua << 16);
        float v1 = __uint_as_float(ua & 0xFFFF0000u);
        x3p[(size_t)(ot * 16 + kg * 4 + 2 * rp) * A2 + ijt * 16 + m16]     = (unsigned short)ua;
        x3p[(size_t)(ot * 16 + kg * 4 + 2 * rp + 1) * A2 + ijt * 16 + m16] = (unsigned short)(ua >> 16);
        sacc[ot][2 * rp]     += v0;
        sacc[ot][2 * rp + 1] += v1;
        qacc[ot][2 * rp]      = fmaf(v0, v0, qacc[ot][2 * rp]);
        qacc[ot][2 * rp + 1]  = fmaf(v1, v1, qacc[ot][2 * rp + 1]);
      }
    }
  }
#pragma unroll
  for (int ot = 0; ot < 2; ot++)
#pragma unroll
    for (int r = 0; r < 4; r++) {
      float sv = sacc[ot][r], qv = qacc[ot][r];
#pragma unroll
      for (int msk = 1; msk < 16; msk <<= 1) {
        sv += __shfl_xor(sv, msk, 64);
        qv += __shfl_xor(qv, msk, 64);
      }
      if (m16 == 0) {
        int o = ot * 16 + kg * 4 + r;
        atomicAdd(&st3[o], sv);
        atomicAdd(&st3[32 + o], qv);
      }
    }
  __syncthreads();
  if (t < 64) atomicAdd(&sums_out[(blk & (NREP - 1)) * REP + 768 + t], st3[t]);
}

// ---------------- K4: bn3 + residual + layout transform ----------------
__global__ __launch_bounds__(256) void k4_out(const float* __restrict__ x,
                                              const unsigned short* __restrict__ x3,
                                              const float* __restrict__ sums,
                                              const float* __restrict__ g3,
                                              const float* __restrict__ b3,
                                              float* __restrict__ out) {
  const int idx4 = blockIdx.x * 256 + threadIdx.x;   // 1,048,576 float4 total
  const int w4 = idx4 & 31;
  int tmp = idx4 >> 5;
  const int h = tmp & 127; tmp >>= 7;
  const int o = tmp & 31;
  const int b = tmp >> 5;
  const int fi = h >> 4, i = h & 15;
  const int fj = w4 >> 2;
  const int j0 = (w4 & 3) * 4;
  const int p   = b * 64 + fi * 8 + fj;
  const int ij0 = i * 16 + j0;
  const float inv = 1.f / 131072.f;
  float m   = rsum16(sums, 768 + o) * inv;
  float var = rsum16(sums, 800 + o) * inv - m * m;
  float sv  = g3[o] * rsqrtf(var + EPS);
  float shv = b3[o] - m * sv;
  float4 xv = *(const float4*)&x[(size_t)idx4 * 4];
  ushort4 u = *(const ushort4*)&x3[((size_t)p * 32 + o) * A2 + ij0];
  float4 r;
  r.x = fmaf(bf2f(u.x), sv, shv) + xv.x;
  r.y = fmaf(bf2f(u.y), sv, shv) + xv.y;
  r.z = fmaf(bf2f(u.z), sv, shv) + xv.z;
  r.w = fmaf(bf2f(u.w), sv, shv) + xv.w;
  *(float4*)&out[(size_t)idx4 * 4] = r;
}

extern "C" void kernel_launch(void* const* d_in, const int* in_sizes, int n_in,
                              void* d_out, int out_size, void* d_ws, size_t ws_size,
                              hipStream_t stream) {
  const float* x  = (const float*)d_in[0];
  const float* s  = (const float*)d_in[1];
  const float* g1 = (const float*)d_in[2];
  const float* b1 = (const float*)d_in[3];
  const float* g2 = (const float*)d_in[4];
  const float* b2 = (const float*)d_in[5];
  const float* g3 = (const float*)d_in[6];
  const float* b3 = (const float*)d_in[7];
  char* base = (char*)d_ws;
  unsigned short* wb1  = (unsigned short*)(base + WB1_B);
  float*          wt2  = (float*)(base + WT2_B);
  unsigned short* x2   = (unsigned short*)(base + X2_B);
  unsigned short* x3   = (unsigned short*)(base + X3_B);
  float*          sums = (float*)(base + SUM_B);
  float* out = (float*)d_out;

  k0_transpose<<<8 * 219, 256, 0, stream>>>(s, wb1, wt2, sums);
  k1_stats<<<P_TOT, 512, 0, stream>>>(x, wb1, sums);
  k2_fused<<<P_TOT, 512, 0, stream>>>(x, wb1, wt2, sums, g1, b1, x2, sums);
  k3_pw2<<<1024, 256, 0, stream>>>(x2, wt2, sums, g2, b2, x3, sums);
  k4_out<<<4096, 256, 0, stream>>>(x, x3, sums, g3, b3, out);
}